// Round 14
// baseline (1205.732 us; speedup 1.0000x reference)
//
#include <hip/hip_runtime.h>

typedef unsigned short u16;
typedef unsigned int   u32;
typedef __bf16    bf16x8 __attribute__((ext_vector_type(8)));
typedef _Float16  f16x8  __attribute__((ext_vector_type(8)));
typedef _Float16  f16x4  __attribute__((ext_vector_type(4)));
typedef __fp16    fp16x2 __attribute__((ext_vector_type(2)));
typedef float     f32x4  __attribute__((ext_vector_type(4)));
typedef u16       u16x4  __attribute__((ext_vector_type(4)));

#define DEV static __device__ __forceinline__

#if __has_builtin(__builtin_amdgcn_mfma_f32_16x16x16f16)
#define HAVE_MFMA16 1
#else
#define HAVE_MFMA16 0
#endif

constexpr int DIMc  = 1024;
constexpr int NHEAD = 16;
constexpr int HDM   = 64;
constexpr int SLENc = 2048;
constexpr int NBAT  = 2;
constexpr int NTOK  = NBAT * SLENc;     // 4096
constexpr int FFD   = 4096;
constexpr int NEXP  = 8;
constexpr int NSLOT = 2 * NTOK;         // 8192
constexpr long TD   = (long)NTOK * DIMc;
constexpr float RSC = 2048.0f;          // residual scale 2^11
constexpr float RSCI = 1.0f / 2048.0f;
constexpr float LOG2E = 1.4426950408889634f;

DEV u16 f2bf(float f) {
  u32 u = __float_as_uint(f);
  u += 0x7fffu + ((u >> 16) & 1u);
  return (u16)(u >> 16);
}
DEV float bf2f(u16 h) { return __uint_as_float(((u32)h) << 16); }
DEV float h2f(u16 u) { union { _Float16 h; u16 u_; } x; x.u_ = u; return (float)x.h; }

// f32 -> f16 high + scaled residual (v ~= h + r/2048, rel err ~2^-22)
DEV void split2v(float v, u16& h, u16& r) {
  _Float16 hh = (_Float16)v;
  float rf = (v - (float)hh) * RSC;
  union { _Float16 h_; u16 u_; } a, b;
  a.h_ = hh; b.h_ = (_Float16)rf;
  h = a.u_; r = b.u_;
}

DEV u32 pkrtz(float a, float b) {
  union { fp16x2 v; u32 u; } x;
  x.v = __builtin_amdgcn_cvt_pkrtz(a, b);
  return x.u;
}

DEV f16x4 mk4(u32 lo, u32 hi) {
  union { u32 u[2]; f16x4 v; } x;
  x.u[0] = lo; x.u[1] = hi;
  return x.v;
}

DEV void async16(const void* g, void* l) {
  __builtin_amdgcn_global_load_lds((const u32*)g, (u32*)l, 16, 0, 0);
}

DEV f32x4 mfma_bf(bf16x8 a, bf16x8 b, f32x4 c) {
  return __builtin_amdgcn_mfma_f32_16x16x32_bf16(a, b, c, 0, 0, 0);
}
DEV f32x4 mfma_h(f16x8 a, f16x8 b, f32x4 c) {
  return __builtin_amdgcn_mfma_f32_16x16x32_f16(a, b, c, 0, 0, 0);
}
#if HAVE_MFMA16
DEV f32x4 mfma16h(f16x4 a, f16x4 b, f32x4 c) {
  return __builtin_amdgcn_mfma_f32_16x16x16f16(a, b, c, 0, 0, 0);
}
#endif

// swizzled fragment read from a [64][64] u16 LDS tile (rows 128B, 16B blocks XOR'd by row&7)
DEV f16x8 ldfragh(const u16 (*T)[64], int row, int blk) {
  return *(const f16x8*)((const u16*)T + row * 64 + ((blk ^ (row & 7)) * 8));
}
// 8B V-fragment for 16x16x16 PV: elems k' = kc*4..+3 of k-block kn, row d
DEV f16x4 ldVfrag4(const u16 (*T)[64], int row, int kn, int kc) {
  const int blk = kn * 2 + (kc >> 1);
  const u16* p = (const u16*)T + row * 64 + ((blk ^ (row & 7)) * 8) + (kc & 1) * 4;
  return *(const f16x4*)p;
}

// fast GELU (tanh form): max abs err ~1e-3, below bf16 storage noise of h
DEV float gelu_fast(float v) {
  float arg = v * fmaf(0.044715f * v, v, 1.0f) * 0.7978845608028654f;
  return v / (1.0f + __expf(-2.0f * arg));
}

// ---------------- elementwise f32 -> 2-way f16 split ----------------
__global__ __launch_bounds__(256) void split2_kernel(
    const float* __restrict__ x, u16* __restrict__ o0, u16* __restrict__ o1, long n) {
  long i = ((long)blockIdx.x * 256 + threadIdx.x) * 4;
  if (i >= n) return;
  f32x4 v = *(const f32x4*)(x + i);
  u16x4 h, r;
#pragma unroll
  for (int j = 0; j < 4; ++j) { u16 a, b; split2v(v[j], a, b); h[j] = a; r[j] = b; }
  *(u16x4*)(o0 + i) = h;
  *(u16x4*)(o1 + i) = r;
}

// ---------------- weight transpose + f16 2-split (W[R][C] -> Wt[C][R]) ----------
__global__ __launch_bounds__(256) void wsplit2_kernel(
    const float* __restrict__ W, u16* __restrict__ t0, u16* __restrict__ t1, int R, int C) {
  __shared__ alignas(16) float tile[32][33];
  const long base = (long)blockIdx.z * R * C;
  const int c0 = blockIdx.x * 32, r0 = blockIdx.y * 32;
  const int tx = threadIdx.x & 31, ty = threadIdx.x >> 5;
#pragma unroll
  for (int i = 0; i < 32; i += 8)
    tile[ty + i][tx] = W[base + (long)(r0 + ty + i) * C + (c0 + tx)];
  __syncthreads();
#pragma unroll
  for (int i = 0; i < 32; i += 8) {
    float v = tile[tx][ty + i];
    long oidx = base + (long)(c0 + ty + i) * R + (r0 + tx);
    u16 a, b; split2v(v, a, b);
    t0[oidx] = a; t1[oidx] = b;
  }
}

// ---------------- weight transpose -> single bf16 plane (MoE experts) ----------
__global__ __launch_bounds__(256) void wsplit1_kernel(
    const float* __restrict__ W, u16* __restrict__ t0, int R, int C) {
  __shared__ alignas(16) float tile[32][33];
  const long base = (long)blockIdx.z * R * C;
  const int c0 = blockIdx.x * 32, r0 = blockIdx.y * 32;
  const int tx = threadIdx.x & 31, ty = threadIdx.x >> 5;
#pragma unroll
  for (int i = 0; i < 32; i += 8)
    tile[ty + i][tx] = W[base + (long)(r0 + ty + i) * C + (c0 + tx)];
  __syncthreads();
#pragma unroll
  for (int i = 0; i < 32; i += 8) {
    long oidx = base + (long)(c0 + ty + i) * R + (r0 + tx);
    t0[oidx] = f2bf(tile[tx][ty + i]);
  }
}

// ---------------- bias concat: [bq|bk|bv] and [bk_c|bv_c] ----------------
__global__ __launch_bounds__(256) void biascat_kernel(
    const float* __restrict__ q, const float* __restrict__ k, const float* __restrict__ v,
    const float* __restrict__ ck, const float* __restrict__ cv,
    float* __restrict__ qkvb, float* __restrict__ kvb) {
  int i = blockIdx.x * 256 + threadIdx.x;
  if (i < 1024) qkvb[i] = q[i];
  else if (i < 2048) qkvb[i] = k[i - 1024];
  else if (i < 3072) qkvb[i] = v[i - 2048];
  else if (i < 4096) kvb[i - 3072] = ck[i - 3072];
  else if (i < 5120) kvb[i - 3072] = cv[i - 4096];
}

// ---------------- V transpose from split planes: V[t][ld] -> Vt[bh][d][s] ------
__global__ __launch_bounds__(256) void vtrans2_kernel(
    const u16* __restrict__ vh, const u16* __restrict__ vr, int ld,
    u16* __restrict__ t0, u16* __restrict__ t1) {
  __shared__ alignas(16) float tile[32][33];
  const int bh = blockIdx.z, b = bh >> 4, h = bh & 15;
  const int s0 = blockIdx.x * 32, d0 = blockIdx.y * 32;
  const int tx = threadIdx.x & 31, ty = threadIdx.x >> 5;
#pragma unroll
  for (int i = 0; i < 32; i += 8) {
    long idx = (long)(b * SLENc + s0 + ty + i) * ld + h * HDM + d0 + tx;
    tile[ty + i][tx] = h2f(vh[idx]) + h2f(vr[idx]) * RSCI;
  }
  __syncthreads();
#pragma unroll
  for (int i = 0; i < 32; i += 8) {
    float v = tile[tx][ty + i];
    long o = ((long)bh * HDM + d0 + ty + i) * SLENc + s0 + tx;
    u16 a, b_; split2v(v, a, b_);
    t0[o] = a; t1[o] = b_;
  }
}

// ---------------- GEMM: C[M][N] = A[M][K] @ Bt[N][K]^T (+bias, epilogue) --------
// MT: M-tile (64 or 128). N-tile fixed 128. SPLIT: f16 2-way split (3 mfma terms).
// BK=32: linear LDS, double-buffered prefetch pipeline (T3-min).
// EPI 0: f32 out; 1: gelu->bf16; 2: ->bf16; 3: f16 2-split planes (Cout,C1)
template<int MT, int BK, bool SPLIT, bool GATHER, int EPI>
__global__ __launch_bounds__(256) void gemm_kernel(
    const u16* __restrict__ A0, const u16* __restrict__ A1,
    const u16* __restrict__ B0, const u16* __restrict__ B1,
    const float* __restrict__ bias, void* __restrict__ Cout, u16* __restrict__ C1,
    int M, int N, int Kd,
    const int* __restrict__ tlist, const int* __restrict__ cnts, const int* __restrict__ offs) {
  constexpr int NP   = SPLIT ? 2 : 1;
  constexpr int NBUF = (BK == 32) ? 2 : 1;  // pipeline only BK=32
  constexpr int RPC  = 512 / BK;            // rows per 1KB staging chunk
  constexpr int ACH  = (MT / RPC) / 4;      // a-chunks per wave
  constexpr int BCH  = (128 / RPC) / 4;     // b-chunks per wave
  constexpr int MREP = MT / 32;             // m-fragments per wave
  constexpr int WRS  = MT / 2;              // per-wave row span
  __shared__ alignas(16) u16 As[NBUF][NP][MT * BK];
  __shared__ alignas(16) u16 Bs[NBUF][NP][128 * BK];

  const int e   = blockIdx.z;
  const int cnt = cnts ? cnts[e] : M;
  const int off = offs ? offs[e] : 0;
  const int m0  = blockIdx.y * MT;
  if (m0 >= cnt) return;
  const int n0  = blockIdx.x * 128;

  const int tid = threadIdx.x;
  const int lane = tid & 63, wid = tid >> 6;
  const int fr = lane & 15, kc = lane >> 4;
  const int wr = wid >> 1, wc = wid & 1;

  const long boff = (long)e * N * Kd;

  int srow, kseg8;
  if constexpr (BK == 32) { srow = lane >> 2; kseg8 = lane & 3; }
  else                    { srow = lane >> 3; kseg8 = (lane & 7) ^ (srow & 7); }

  long aoff[ACH], boff_[BCH];
#pragma unroll
  for (int c = 0; c < ACH; ++c) {
    const int row = (wid * ACH + c) * RPC + srow;
    long ar;
    if (GATHER) {
      int idx = m0 + row; if (idx >= cnt) idx = cnt - 1;
      ar = tlist[off + idx];
    } else {
      ar = (long)(off + m0 + row);
    }
    aoff[c] = ar * Kd + kseg8 * 8;
  }
#pragma unroll
  for (int c = 0; c < BCH; ++c) {
    const int row = (wid * BCH + c) * RPC + srow;
    boff_[c] = boff + (long)(n0 + row) * Kd + kseg8 * 8;
  }

  f32x4 acc[MREP][4], acc1[MREP][4];
#pragma unroll
  for (int m = 0; m < MREP; ++m)
#pragma unroll
    for (int n = 0; n < 4; ++n) { acc[m][n] = f32x4{0.f,0.f,0.f,0.f}; acc1[m][n] = f32x4{0.f,0.f,0.f,0.f}; }

  auto stage = [&](int kt, int bufi) {
    const int k0 = kt * BK;
#pragma unroll
    for (int c = 0; c < ACH; ++c) {
      const int chunk = wid * ACH + c;
      async16(A0 + aoff[c] + k0, &As[bufi][0][chunk * 512]);
      if constexpr (SPLIT) async16(A1 + aoff[c] + k0, &As[bufi][1][chunk * 512]);
    }
#pragma unroll
    for (int c = 0; c < BCH; ++c) {
      const int chunk = wid * BCH + c;
      async16(B0 + boff_[c] + k0, &Bs[bufi][0][chunk * 512]);
      if constexpr (SPLIT) async16(B1 + boff_[c] + k0, &Bs[bufi][1][chunk * 512]);
    }
  };

  auto compute = [&](int bufi) {
    if constexpr (BK == 32) {
      if constexpr (SPLIT) {
        f16x8 a0[MREP], a1[MREP];
#pragma unroll
        for (int m = 0; m < MREP; ++m) {
          const int idx = (wr * WRS + m * 16 + fr) * 32 + kc * 8;
          a0[m] = *(const f16x8*)&As[bufi][0][idx];
          a1[m] = *(const f16x8*)&As[bufi][1][idx];
        }
#pragma unroll
        for (int n = 0; n < 4; ++n) {
          const int idx = (wc * 64 + n * 16 + fr) * 32 + kc * 8;
          f16x8 b0 = *(const f16x8*)&Bs[bufi][0][idx];
          f16x8 b1 = *(const f16x8*)&Bs[bufi][1][idx];
#pragma unroll
          for (int m = 0; m < MREP; ++m) {
            acc[m][n]  = mfma_h(a0[m], b0, acc[m][n]);
            acc1[m][n] = mfma_h(a0[m], b1, acc1[m][n]);
            acc1[m][n] = mfma_h(a1[m], b0, acc1[m][n]);
          }
        }
      } else {
        bf16x8 a0[MREP];
#pragma unroll
        for (int m = 0; m < MREP; ++m)
          a0[m] = *(const bf16x8*)&As[bufi][0][(wr * WRS + m * 16 + fr) * 32 + kc * 8];
#pragma unroll
        for (int n = 0; n < 4; ++n) {
          bf16x8 b0 = *(const bf16x8*)&Bs[bufi][0][(wc * 64 + n * 16 + fr) * 32 + kc * 8];
#pragma unroll
          for (int m = 0; m < MREP; ++m)
            acc[m][n] = mfma_bf(a0[m], b0, acc[m][n]);
        }
      }
    } else {
      // BK=64, bf16 only. XOR-swizzled reads: blk' = blk ^ (row&7); row&7 == fr&7.
#pragma unroll
      for (int ksub = 0; ksub < 2; ++ksub) {
        bf16x8 a0[MREP];
#pragma unroll
        for (int m = 0; m < MREP; ++m) {
          const int row = wr * WRS + m * 16 + fr;
          a0[m] = *(const bf16x8*)&As[0][0][row * 64 + (((ksub << 2) | kc) ^ (fr & 7)) * 8];
        }
#pragma unroll
        for (int n = 0; n < 4; ++n) {
          const int row = wc * 64 + n * 16 + fr;
          bf16x8 b0 = *(const bf16x8*)&Bs[0][0][row * 64 + (((ksub << 2) | kc) ^ (fr & 7)) * 8];
#pragma unroll
          for (int m = 0; m < MREP; ++m)
            acc[m][n] = mfma_bf(a0[m], b0, acc[m][n]);
        }
      }
    }
  };

  const int NK = Kd / BK;
  if constexpr (BK == 32) {
    // T3-min pipelined double buffer: prefetch kt+1 before computing kt.
    stage(0, 0);
    int cur = 0;
    for (int kt = 0; kt < NK; ++kt) {
      __syncthreads();                       // drains vmcnt -> tile kt ready; all waves done with other buf
      if (kt + 1 < NK) stage(kt + 1, cur ^ 1);
      compute(cur);
      cur ^= 1;
    }
  } else {
    for (int kt = 0; kt < NK; ++kt) {
      __syncthreads();
      stage(kt, 0);
      __syncthreads();
      compute(0);
    }
  }

  const float* bvec = bias + (long)e * N;
#pragma unroll
  for (int m = 0; m < MREP; ++m) {
#pragma unroll
    for (int j = 0; j < 4; ++j) {
      const int r = m0 + wr * WRS + m * 16 + kc * 4 + j;
      if (r >= cnt) continue;
      const long orow = (long)(off + r) * N;
#pragma unroll
      for (int n = 0; n < 4; ++n) {
        const int col = n0 + wc * 64 + n * 16 + fr;
        float v = acc[m][n][j];
        if constexpr (SPLIT) v += acc1[m][n][j] * RSCI;
        v += bvec[col];
        if constexpr (EPI == 0) {
          ((float*)Cout)[orow + col] = v;
        } else if constexpr (EPI == 1) {
          ((u16*)Cout)[orow + col] = f2bf(gelu_fast(v));
        } else if constexpr (EPI == 2) {
          ((u16*)Cout)[orow + col] = f2bf(v);
        } else {
          u16 a_, b_; split2v(v, a_, b_);
          ((u16*)Cout)[orow + col] = a_;
          C1[orow + col] = b_;
        }
      }
    }
  }
}

// ---------------- MFMA flash attention, f16 2-split, QBLK=128 / 8 waves --------
#if !HAVE_MFMA16
DEV f16x8 gather_fragh(u32 a0, u32 a1, u32 b0, u32 b1, int lane) {
  const int kc = lane >> 4;
  const int base = (lane & 15) + ((kc & 1) << 5);
  union { u32 u[4]; f16x8 v; } r;
  u32 s00 = (u32)__shfl((int)a0, base, 64);
  u32 s01 = (u32)__shfl((int)a1, base, 64);
  u32 s10 = (u32)__shfl((int)b0, base, 64);
  u32 s11 = (u32)__shfl((int)b1, base, 64);
  u32 t00 = (u32)__shfl((int)a0, base + 16, 64);
  u32 t01 = (u32)__shfl((int)a1, base + 16, 64);
  u32 t10 = (u32)__shfl((int)b0, base + 16, 64);
  u32 t11 = (u32)__shfl((int)b1, base + 16, 64);
  const bool hi = (kc >> 1) != 0;
  r.u[0] = hi ? s10 : s00;
  r.u[1] = hi ? s11 : s01;
  r.u[2] = hi ? t10 : t00;
  r.u[3] = hi ? t11 : t01;
  return r.v;
}
#endif

template<bool CAUSAL>
__global__ __launch_bounds__(512, 4) void attn2_kernel(
    const u16* __restrict__ Qh, const u16* __restrict__ Qr, int qld,
    const u16* __restrict__ Kh, const u16* __restrict__ Kr, int kld,
    const u16* __restrict__ Vh, const u16* __restrict__ Vr,
    u16* __restrict__ OH, u16* __restrict__ OR) {
  __shared__ alignas(16) u16 KQs[2][2][64][64];   // [buf][plane][row][col]
  __shared__ alignas(16) u16 Vts[2][2][64][64];

  // LPT schedule for causal: heavy blocks (large qt => most k-tiles) launch first
  const int qt = CAUSAL ? ((int)gridDim.x - 1 - (int)blockIdx.x) : (int)blockIdx.x;
  const int h = blockIdx.y, b = blockIdx.z;
  const int tid = threadIdx.x, lane = tid & 63, w = tid >> 6;   // w in 0..7
  const int wq = w >> 2, wl = w & 3;          // q-half, role within half
  const int fr = lane & 15, kc = lane >> 4;
  const int q0 = qt * 128;
  const int qrow = wq * 64 + wl * 16 + fr;    // q row within block (0..127)
  const int qglob = q0 + qrow;                // global q row (causal mask RHS)
  const long qbase = (long)(b * SLENc) * qld + h * HDM;
  const long kbase = (long)(b * SLENc) * kld + h * HDM;
  const long obase = (long)(b * SLENc) * DIMc + h * HDM;
  const long vtbase = (long)(b * NHEAD + h) * HDM * SLENc;
  const int r = lane >> 3, blk = (lane & 7) ^ r;

  auto stageKV = [&](int kt, int bufi) {
    // 8 waves: wave w loads rows 8w..8w+7 of the 64-row K and V tiles
#pragma unroll
    for (int p = 0; p < 2; ++p) {
      const u16* gp = (p == 0 ? Kh : Kr);
      async16(gp + kbase + (long)(kt * 64 + 8 * w + r) * kld + blk * 8, &KQs[bufi][p][8 * w][0]);
    }
    const long vrow = vtbase + kt * 64;
#pragma unroll
    for (int p = 0; p < 2; ++p) {
      const u16* gp = (p == 0 ? Vh : Vr);
      async16(gp + vrow + (long)(8 * w + r) * SLENc + blk * 8, &Vts[bufi][p][8 * w][0]);
    }
  };

  // ---- prologue: stage 128 Q rows (half0 -> KQs[0], half1 -> Vts[0]) ----
#pragma unroll
  for (int hh = 0; hh < 2; ++hh) {
#pragma unroll
    for (int p = 0; p < 2; ++p) {
      const u16* gp = (p == 0 ? Qh : Qr);
      u16* dst = hh == 0 ? &KQs[0][p][8 * w][0] : &Vts[0][p][8 * w][0];
      async16(gp + qbase + (long)(q0 + hh * 64 + 8 * w + r) * qld + blk * 8, dst);
    }
  }
  __syncthreads();
  f16x8 qf0[2], qf1[2];
  {
    const u16 (*Q0)[64] = (wq == 0) ? KQs[0][0] : Vts[0][0];
    const u16 (*Q1)[64] = (wq == 0) ? KQs[0][1] : Vts[0][1];
#pragma unroll
    for (int s = 0; s < 2; ++s) {
      qf0[s] = ldfragh(Q0, wl * 16 + fr, s * 4 + kc);
      qf1[s] = ldfragh(Q1, wl * 16 + fr, s * 4 + kc);
    }
  }
  // prefetch K/V tile 0 into buf1 (doesn't touch buf0 just read)
  stageKV(0, 1);

  f32x4 accO0[4], accO1[4];
#pragma unroll
  for (int dn = 0; dn < 4; ++dn) { accO0[dn] = f32x4{0.f,0.f,0.f,0.f}; accO1[dn] = f32x4{0.f,0.f,0.f,0.f}; }
  float m_ = -3e38f, l_ = 0.f;   // m_ in log2 domain

  const int nkt = CAUSAL ? (2 * qt + 2) : (SLENc / 64);
  int cur = 1;
  for (int kt = 0; kt < nkt; ++kt) {
    __syncthreads();                        // tile kt landed in bufs[cur]; all waves done with bufs[cur^1]
    if (kt + 1 < nkt) stageKV(kt + 1, cur ^ 1);

    // ---- QK^T (swapped): sc at (k = kn*16 + kc*4 + j, q = fr) ----
    f32x4 sc0[4], sc1[4];
#pragma unroll
    for (int kn = 0; kn < 4; ++kn) { sc0[kn] = f32x4{0.f,0.f,0.f,0.f}; sc1[kn] = f32x4{0.f,0.f,0.f,0.f}; }
    __builtin_amdgcn_s_setprio(1);
#pragma unroll
    for (int kn = 0; kn < 4; ++kn)
#pragma unroll
      for (int s = 0; s < 2; ++s) {
        f16x8 ah = ldfragh(KQs[cur][0], kn * 16 + fr, s * 4 + kc);
        f16x8 ar = ldfragh(KQs[cur][1], kn * 16 + fr, s * 4 + kc);
        sc0[kn] = mfma_h(ah, qf0[s], sc0[kn]);
        sc1[kn] = mfma_h(ah, qf1[s], sc1[kn]);
        sc1[kn] = mfma_h(ar, qf0[s], sc1[kn]);
      }
    __builtin_amdgcn_s_setprio(0);

    // ---- online softmax in log2 domain (per-lane row q = fr) ----
    constexpr float SCL = 0.125f * LOG2E, SCL2 = 0.125f * RSCI * LOG2E;
    float p_[4][4];
    float mx = -3e38f;
#pragma unroll
    for (int kn = 0; kn < 4; ++kn)
#pragma unroll
      for (int j = 0; j < 4; ++j) {
        float sv = fmaf(sc0[kn][j], SCL, sc1[kn][j] * SCL2);
        if (CAUSAL) {
          if (kt * 64 + kn * 16 + kc * 4 + j > qglob) sv = -3e38f;  // absolute key idx vs global q idx
        }
        p_[kn][j] = sv;
        mx = fmaxf(mx, sv);
      }
    mx = fmaxf(mx, __shfl_xor(mx, 16, 64));
    mx = fmaxf(mx, __shfl_xor(mx, 32, 64));
    // T13 defer-rescale: skip when max growth fits 2^11.54 (= e^8) headroom
    if (!__all(mx <= m_ + 11.5415603f)) {
      const float mn = fmaxf(m_, mx);
      const float corr = exp2f(m_ - mn);
      m_ = mn;
      l_ *= corr;
#pragma unroll
      for (int dn = 0; dn < 4; ++dn) { accO0[dn] *= corr; accO1[dn] *= corr; }
    }
    float rs = 0.f;
#pragma unroll
    for (int kn = 0; kn < 4; ++kn)
#pragma unroll
      for (int j = 0; j < 4; ++j) {
        float p = exp2f(p_[kn][j] - m_);
        p_[kn][j] = p;
        rs += p;
      }
    rs += __shfl_xor(rs, 16, 64);
    rs += __shfl_xor(rs, 32, 64);
    l_ += rs;

#if HAVE_MFMA16
    // ---- PV via 16x16x16 mfma: B-frag (P column q=fr, k=kc*4+j) is lane-local ----
#pragma unroll
    for (int kn = 0; kn < 4; ++kn) {
      u32 hp0 = pkrtz(p_[kn][0], p_[kn][1]);
      u32 hp1 = pkrtz(p_[kn][2], p_[kn][3]);
      float h0 = h2f((u16)hp0), h1 = h2f((u16)(hp0 >> 16));
      float h2_ = h2f((u16)hp1), h3 = h2f((u16)(hp1 >> 16));
      u32 rp0 = pkrtz((p_[kn][0] - h0) * RSC, (p_[kn][1] - h1) * RSC);
      u32 rp1 = pkrtz((p_[kn][2] - h2_) * RSC, (p_[kn][3] - h3) * RSC);
      f16x4 ph = mk4(hp0, hp1), pr = mk4(rp0, rp1);
      __builtin_amdgcn_s_setprio(1);
#pragma unroll
      for (int dn = 0; dn < 4; ++dn) {
        f16x4 vh = ldVfrag4(Vts[cur][0], dn * 16 + fr, kn, kc);
        f16x4 vr = ldVfrag4(Vts[cur][1], dn * 16 + fr, kn, kc);
        accO0[dn] = mfma16h(vh, ph, accO0[dn]);
        accO1[dn] = mfma16h(vh, pr, accO1[dn]);
        accO1[dn] = mfma16h(vr, ph, accO1[dn]);
      }
      __builtin_amdgcn_s_setprio(0);
    }
#else
    // ---- fallback: split P, redistribute via lane gathers, 16x16x32 PV ----
    u32 hpk[4][2], rpk[4][2];
#pragma unroll
    for (int kn = 0; kn < 4; ++kn)
#pragma unroll
      for (int jp = 0; jp < 2; ++jp) {
        float p0 = p_[kn][2 * jp], p1 = p_[kn][2 * jp + 1];
        u32 hp = pkrtz(p0, p1);
        float h0 = h2f((u16)hp), h1 = h2f((u16)(hp >> 16));
        u32 rp = pkrtz((p0 - h0) * RSC, (p1 - h1) * RSC);
        hpk[kn][jp] = hp;
        rpk[kn][jp] = rp;
      }
#pragma unroll
    for (int s = 0; s < 2; ++s) {
      f16x8 ph = gather_fragh(hpk[2 * s][0], hpk[2 * s][1], hpk[2 * s + 1][0], hpk[2 * s + 1][1], lane);
      f16x8 pr = gather_fragh(rpk[2 * s][0], rpk[2 * s][1], rpk[2 * s + 1][0], rpk[2 * s + 1][1], lane);
      __builtin_amdgcn_s_setprio(1);
#pragma unroll
      for (int dn = 0; dn < 4; ++dn) {
        f16x8 vh = ldfragh(Vts[cur][0], dn * 16 + fr, s * 4 + kc);
        f16x8 vr = ldfragh(Vts[cur][1], dn * 16 + fr, s * 4 + kc);
        accO0[dn] = mfma_h(vh, ph, accO0[dn]);
        accO1[dn] = mfma_h(vh, pr, accO1[dn]);
        accO1[dn] = mfma_h(vr, ph, accO1[dn]);
      }
      __builtin_amdgcn_s_setprio(0);
    }
#endif
    cur ^= 1;
  }

  const float inv = 1.0f / l_;
#pragma unroll
  for (int dn = 0; dn < 4; ++dn) {
    u16x4 hv, rv;
#pragma unroll
    for (int j = 0; j < 4; ++j) {
      float o = (accO0[dn][j] + accO1[dn][j] * RSCI) * inv;
      u16 a_, b_; split2v(o, a_, b_);
      hv[j] = a_; rv[j] = b_;
    }
    const long oidx = obase + (long)(q0 + qrow) * DIMc + dn * 16 + kc * 4;
    *(u16x4*)&OH[oidx] = hv;
    *(u16x4*)&OR[oidx] = rv;
  }
}

// ---------------- residual + layernorm (+ optional split outputs) ----------------
template<int NS>
__global__ __launch_bounds__(256) void resln_kernel(
    const float* __restrict__ resid, const float* __restrict__ proj,
    const float* __restrict__ gam, const float* __restrict__ bet,
    float* __restrict__ yout, u16* __restrict__ s0, u16* __restrict__ s1) {
  __shared__ float red[4];
  const int t = blockIdx.x, tid = threadIdx.x;
  const long base = (long)t * DIMc;
  float v[4];
#pragma unroll
  for (int i = 0; i < 4; ++i) {
    int d = tid + i * 256;
    v[i] = resid[base + d] + proj[base + d];
  }
  float s = v[0] + v[1] + v[2] + v[3];
#pragma unroll
  for (int o = 32; o; o >>= 1) s += __shfl_xor(s, o, 64);
  if ((tid & 63) == 0) red[tid >> 6] = s;
  __syncthreads();
  const float mean = (red[0] + red[1] + red[2] + red[3]) * (1.0f / DIMc);
  __syncthreads();
  float q = 0.f;
#pragma unroll
  for (int i = 0; i < 4; ++i) { float d_ = v[i] - mean; q += d_ * d_; }
#pragma unroll
  for (int o = 32; o; o >>= 1) q += __shfl_xor(q, o, 64);
  if ((tid & 63) == 0) red[tid >> 6] = q;
  __syncthreads();
  const float var = (red[0] + red[1] + red[2] + red[3]) * (1.0f / DIMc);
  const float inv = rsqrtf(var + 1e-5f);
#pragma unroll
  for (int i = 0; i < 4; ++i) {
    int d = tid + i * 256;
    float y = (v[i] - mean) * inv * gam[d] + bet[d];
    yout[base + d] = y;
    if constexpr (NS == 1) s0[base + d] = f2bf(y);
    if constexpr (NS == 2) {
      u16 a, b; split2v(y, a, b);
      s0[base + d] = a; s1[base + d] = b;
    }
  }
}

// ---------------- residual + LN2 + fused router (logits, top-2, counts) --------
__global__ __launch_bounds__(256) void resln_router_kernel(
    const float* __restrict__ resid, const float* __restrict__ proj,
    const float* __restrict__ gam, const float* __restrict__ bet,
    const float* __restrict__ rw, const float* __restrict__ rb,
    float* __restrict__ yout, u16* __restrict__ s0,
    int* __restrict__ topi, float* __restrict__ topw, int* __restrict__ cnt) {
  __shared__ float red[4];
  __shared__ float rpart[4][8];
  const int t = blockIdx.x, tid = threadIdx.x;
  const int lane = tid & 63, wv = tid >> 6;
  const long base = (long)t * DIMc;
  float v[4];
#pragma unroll
  for (int i = 0; i < 4; ++i) {
    int d = tid + i * 256;
    v[i] = resid[base + d] + proj[base + d];
  }
  float s = v[0] + v[1] + v[2] + v[3];
#pragma unroll
  for (int o = 32; o; o >>= 1) s += __shfl_xor(s, o, 64);
  if (lane == 0) red[wv] = s;
  __syncthreads();
  const float mean = (red[0] + red[1] + red[2] + red[3]) * (1.0f / DIMc);
  __syncthreads();
  float q = 0.f;
#pragma unroll
  for (int i = 0; i < 4; ++i) { float d_ = v[i] - mean; q += d_ * d_; }
#pragma unroll
  for (int o = 32; o; o >>= 1) q += __shfl_xor(q, o, 64);
  if (lane == 0) red[wv] = q;
  __syncthreads();
  const float var = (red[0] + red[1] + red[2] + red[3]) * (1.0f / DIMc);
  const float inv = rsqrtf(var + 1e-5f);
  float part[8] = {};
#pragma unroll
  for (int i = 0; i < 4; ++i) {
    int d = tid + i * 256;
    float y = (v[i] - mean) * inv * gam[d] + bet[d];
    yout[base + d] = y;
    s0[base + d] = f2bf(y);
    const f32x4* wp = (const f32x4*)&rw[d * 8];
    f32x4 w0 = wp[0], w1 = wp[1];
    part[0] += y * w0[0]; part[1] += y * w0[1]; part[2] += y * w0[2]; part[3] += y * w0[3];
    part[4] += y * w1[0]; part[5] += y * w1[1]; part[6] += y * w1[2]; part[7] += y * w1[3];
  }
#pragma unroll
  for (int o = 32; o; o >>= 1)
#pragma unroll
    for (int e = 0; e < 8; ++e) part[e] += __shfl_xor(part[e], o, 64);
  if (lane == 0)
#pragma unroll
    for (int e = 0; e < 8; ++e) rpart[wv][e] = part[e];
  __syncthreads();
  if (tid == 0) {
    float lg[8];
#pragma unroll
    for (int e = 0; e < 8; ++e)
      lg[e] = rpart[0][e] + rpart[1][e] + rpart[2][e] + rpart[3][e] + rb[e];
    int i1 = 0;
#pragma unroll
    for (int e = 1; e < 8; ++e) if (lg[e] > lg[i1]) i1 = e;
    int i2 = (i1 == 0) ? 1 : 0;
#pragma unroll
    for (int e = 0; e < 8; ++e) if (e != i1 && lg[e] > lg[i2]) i2 = e;
    float mx = lg[i1], ps = 0.f, p[8];
#pragma unroll
    for (int e = 0; e < 8; ++e) { p[e] = __expf(lg[e] - mx); ps += p[e]; }
    float p1 = p[i1] / ps, p2 = p[i2] / ps;
    float e2 = __expf(p2 - p1);
    float w1 = 1.0f / (1.0f + e2);
    topi[t * 2] = i1; topi[t * 2 + 1] = i2;
    topw[t * 2] = w1; topw[t * 2 + 1] = e2 * w1;
    atomicAdd(&cnt[i1], 1); atomicAdd(&cnt[i2], 1);
  }
}

__global__ void scan_kernel(const int* __restrict__ cnt, int* __restrict__ offs, int* __restrict__ pos) {
  if (threadIdx.x == 0) {
    int a = 0;
    for (int e = 0; e < NEXP; ++e) { offs[e] = a; a += cnt[e]; }
  }
  if (threadIdx.x < NEXP) pos[threadIdx.x] = 0;
}

__global__ __launch_bounds__(256) void fill_kernel(
    const int* __restrict__ topi, const int* __restrict__ offs, int* __restrict__ pos,
    int* __restrict__ tlist, int* __restrict__ slotof) {
  int t = blockIdx.x * 256 + threadIdx.x;
  if (t >= NTOK) return;
#pragma unroll
  for (int k = 0; k < 2; ++k) {
    int e = topi[t * 2 + k];
    int pp = atomicAdd(&pos[e], 1);
    int s = offs[e] + pp;
    tlist[s] = t;
    slotof[t * 2 + k] = s;
  }
}

// ---------------- final: combine experts + residual + LN3 -> f32 out ----------------
__global__ __launch_bounds__(256) void final_kernel(
    const float* __restrict__ x2, const u16* __restrict__ eo,
    const int* __restrict__ slotof, const float* __restrict__ topw,
    const float* __restrict__ gam, const float* __restrict__ bet, float* __restrict__ out) {
  __shared__ float red[4];
  const int t = blockIdx.x, tid = threadIdx.x;
  const long base = (long)t * DIMc;
  const int s0 = slotof[t * 2], s1 = slotof[t * 2 + 1];
  const float w0 = topw[t * 2], w1 = topw[t * 2 + 1];
  float v[4];
#pragma unroll
  for (int i = 0; i < 4; ++i) {
    int d = tid + i * 256;
    float moe = w0 * bf2f(eo[(long)s0 * DIMc + d]) + w1 * bf2f(eo[(long)s1 * DIMc + d]);
    v[i] = x2[base + d] + moe;
  }
  float s = v[0] + v[1] + v[2] + v[3];
#pragma unroll
  for (int o = 32; o; o >>= 1) s += __shfl_xor(s, o, 64);
  if ((tid & 63) == 0) red[tid >> 6] = s;
  __syncthreads();
  const float mean = (red[0] + red[1] + red[2] + red[3]) * (1.0f / DIMc);
  __syncthreads();
  float q = 0.f;
#pragma unroll
  for (int i = 0; i < 4; ++i) { float d_ = v[i] - mean; q += d_ * d_; }
#pragma unroll
  for (int o = 32; o; o >>= 1) q += __shfl_xor(q, o, 64);
  if ((tid & 63) == 0) red[tid >> 6] = q;
  __syncthreads();
  const float var = (red[0] + red[1] + red[2] + red[3]) * (1.0f / DIMc);
  const float inv = rsqrtf(var + 1e-5f);
#pragma unroll
  for (int i = 0; i < 4; ++i) {
    int d = tid + i * 256;
    out[base + d] = (v[i] - mean) * inv * gam[d] + bet[d];
  }
}

// ---------------- host orchestration ----------------
extern "C" void kernel_launch(void* const* d_in, const int* in_sizes, int n_in,
                              void* d_out, int out_size, void* d_ws, size_t ws_size,
                              hipStream_t stream) {
  (void)in_sizes; (void)n_in; (void)out_size; (void)ws_size;
  const float* x     = (const float*)d_in[0];
  const float* enc   = (const float*)d_in[1];
  const float* aw[8] = {(const float*)d_in[2],  (const float*)d_in[4],  (const float*)d_in[6],  (const float*)d_in[8],
                        (const float*)d_in[10], (const float*)d_in[12], (const float*)d_in[14], (const float*)d_in[16]};
  const float* ab[8] = {(const float*)d_in[3],  (const float*)d_in[5],  (const float*)d_in[7],  (const float*)d_in[9],
                        (const float*)d_in[11], (const float*)d_in[13], (const float*)d_in[15], (const float*)d_in[17]};
  const float* ln1_g = (const float*)d_in[18]; const float* ln1_b = (const float*)d_in[19];
  const float* ln2_g = (const float*)d_in[20]; const float* ln2_b = (const float*)d_in[21];
  const float* ln3_g = (const float*)d_in[22]; const float* ln3_b = (const float*)d_in[23];
  const float* rw    = (const float*)d_in[24]; const float* rb    = (const float*)d_in[25];
  const float* e_w1  = (const float*)d_in[26]; const float* e_b1  = (const float*)d_in[27];
  const float* e_w2  = (const float*)d_in[28]; const float* e_b2  = (const float*)d_in[29];

  char* basep = (char*)d_ws;
  size_t offb = 0;
  auto alloc = [&](size_t nbytes) -> void* {
    void* r = basep + offb;
    offb += (nbytes + 255) & ~(size_t)255;
    return r;
  };

  const size_t PLANE_BF = (size_t)TD * 2;   // 8 MB u16 plane
  const size_t PLANE_F  = (size_t)TD * 4;   // 16 MB f32 plane
  const size_t WPLANE   = (size_t)DIMc * DIMc * 2;  // 2 MB weight plane

  u16 *xs0 = (u16*)alloc(PLANE_BF), *xs1 = (u16*)alloc(PLANE_BF);
  u16 *es0 = (u16*)alloc(PLANE_BF), *es1 = (u16*)alloc(PLANE_BF);
  u16 *os0 = (u16*)alloc(PLANE_BF), *os1 = (u16*)alloc(PLANE_BF);
  u16 *wqkv0 = (u16*)alloc(3 * WPLANE), *wqkv1 = (u16*)alloc(3 * WPLANE);
  u16 *wkv0  = (u16*)alloc(2 * WPLANE), *wkv1  = (u16*)alloc(2 * WPLANE);
  u16 *wq0   = (u16*)alloc(WPLANE),     *wq1   = (u16*)alloc(WPLANE);
  u16 *wo10  = (u16*)alloc(WPLANE),     *wo11  = (u16*)alloc(WPLANE);
  u16 *wo20  = (u16*)alloc(WPLANE),     *wo21  = (u16*)alloc(WPLANE);
  u16* w1t = (u16*)alloc((size_t)NEXP * FFD * DIMc * 2);
  u16* w2t = (u16*)alloc((size_t)NEXP * DIMc * FFD * 2);
  u16 *QKVh = (u16*)alloc(3 * PLANE_BF), *QKVr = (u16*)alloc(3 * PLANE_BF);
  u16 *KVh  = (u16*)alloc(2 * PLANE_BF), *KVr  = (u16*)alloc(2 * PLANE_BF);
  u16 *Qch  = (u16*)alloc(PLANE_BF),     *Qcr  = (u16*)alloc(PLANE_BF);
  u16 *Vth  = (u16*)alloc(PLANE_BF),     *Vtr  = (u16*)alloc(PLANE_BF);
  float* qkvb = (float*)alloc(3072 * 4);
  float* kvb  = (float*)alloc(2048 * 4);
  float* aout = (float*)alloc(PLANE_F);
  float* x1   = (float*)alloc(PLANE_F);
  float* x2   = (float*)alloc(PLANE_F);
  u16*   x2h  = (u16*)alloc(PLANE_BF);
  u16*   hbuf = (u16*)alloc((size_t)(NSLOT + 128) * FFD * 2);
  u16*   eo   = (u16*)alloc((size_t)NSLOT * DIMc * 2);
  int*   topi   = (int*)alloc(NSLOT * 4);
  float* topwp  = (float*)alloc(NSLOT * 4);
  int*   tlist  = (int*)alloc(NSLOT * 4);
  int*   slotof = (int*)alloc(NSLOT * 4);
  int*   cnt    = (int*)alloc(NEXP * 4);
  int*   offs   = (int*)alloc(NEXP * 4);
  int*   pos    = (int*)alloc(NEXP * 4);

  (void)hipMemsetAsync(cnt, 0, NEXP * sizeof(int), stream);

  const int SB = (int)(TD / 4 / 256);
  split2_kernel<<<SB, 256, 0, stream>>>(x, xs0, xs1, TD);
  split2_kernel<<<SB, 256, 0, stream>>>(enc, es0, es1, TD);
  // stacked weight planes: self QKV rows 0..3071; cross KV rows 0..2047
  for (int s = 0; s < 3; ++s)
    wsplit2_kernel<<<dim3(32, 32, 1), 256, 0, stream>>>(aw[s], wqkv0 + (size_t)s * DIMc * DIMc, wqkv1 + (size_t)s * DIMc * DIMc, DIMc, DIMc);
  wsplit2_kernel<<<dim3(32, 32, 1), 256, 0, stream>>>(aw[5], wkv0, wkv1, DIMc, DIMc);
  wsplit2_kernel<<<dim3(32, 32, 1), 256, 0, stream>>>(aw[6], wkv0 + (size_t)DIMc * DIMc, wkv1 + (size_t)DIMc * DIMc, DIMc, DIMc);
  wsplit2_kernel<<<dim3(32, 32, 1), 256, 0, stream>>>(aw[4], wq0, wq1, DIMc, DIMc);
  wsplit2_kernel<<<dim3(32, 32, 1), 256, 0, stream>>>(aw[3], wo10, wo11, DIMc, DIMc);
  wsplit2_kernel<<<dim3(32, 32, 1), 256, 0, stream>>>(aw[7], wo20, wo21, DIMc, DIMc);
  wsplit1_kernel<<<dim3(FFD / 32, DIMc / 32, NEXP), 256, 0, stream>>>(e_w1, w1t, DIMc, FFD);
  wsplit1_kernel<<<dim3(DIMc / 32, FFD / 32, NEXP), 256, 0, stream>>>(e_w2, w2t, FFD, DIMc);
  biascat_kernel<<<20, 256, 0, stream>>>(ab[0], ab[1], ab[2], ab[5], ab[6], qkvb, kvb);

  const dim3 gproj(DIMc / 128, NTOK / 64, 1);        // MT=64
  const dim3 gqkv(3 * DIMc / 128, NTOK / 64, 1);     // MT=64
  const dim3 gkv(2 * DIMc / 128, NTOK / 64, 1);      // MT=64
  const dim3 gattn(SLENc / 128, NHEAD, NBAT);        // QBLK=128, 512 blocks
  const dim3 gvt(SLENc / 32, HDM / 32, NBAT * NHEAD);

  // ---- self-attention ----
  gemm_kernel<64, 32, true, false, 3><<<gqkv, 256, 0, stream>>>(xs0, xs1, wqkv0, wqkv1, qkvb, QKVh, QKVr, NTOK, 3 * DIMc, DIMc, nullptr, nullptr, nullptr);
  vtrans2_kernel<<<gvt, 256, 0, stream>>>(QKVh + 2048, QKVr + 2048, 3 * DIMc, Vth, Vtr);
  attn2_kernel<true><<<gattn, 512, 0, stream>>>(QKVh, QKVr, 3 * DIMc, QKVh + 1024, QKVr + 1024, 3 * DIMc, Vth, Vtr, os0, os1);
  gemm_kernel<64, 32, true, false, 0><<<gproj, 256, 0, stream>>>(os0, os1, wo10, wo11, ab[3], aout, nullptr, NTOK, DIMc, DIMc, nullptr, nullptr, nullptr);
  resln_kernel<2><<<NTOK, 256, 0, stream>>>(x, aout, ln1_g, ln1_b, x1, xs0, xs1);
  // ---- cross-attention ----
  gemm_kernel<64, 32, true, false, 3><<<gproj, 256, 0, stream>>>(xs0, xs1, wq0, wq1, ab[4], Qch, Qcr, NTOK, DIMc, DIMc, nullptr, nullptr, nullptr);
  gemm_kernel<64, 32, true, false, 3><<<gkv, 256, 0, stream>>>(es0, es1, wkv0, wkv1, kvb, KVh, KVr, NTOK, 2 * DIMc, DIMc, nullptr, nullptr, nullptr);
  vtrans2_kernel<<<gvt, 256, 0, stream>>>(KVh + 1024, KVr + 1024, 2 * DIMc, Vth, Vtr);
  attn2_kernel<false><<<gattn, 512, 0, stream>>>(Qch, Qcr, DIMc, KVh, KVr, 2 * DIMc, Vth, Vtr, os0, os1);
  gemm_kernel<64, 32, true, false, 0><<<gproj, 256, 0, stream>>>(os0, os1, wo20, wo21, ab[7], aout, nullptr, NTOK, DIMc, DIMc, nullptr, nullptr, nullptr);
  // ---- LN2 + fused router ----
  resln_router_kernel<<<NTOK, 256, 0, stream>>>(x1, aout, ln2_g, ln2_b, rw, rb, x2, x2h, topi, topwp, cnt);
  // ---- MoE (MT=64, BK=32 pipelined: 24KB LDS, more blocks/CU for latency hiding) ----
  scan_kernel<<<1, 64, 0, stream>>>(cnt, offs, pos);
  fill_kernel<<<NTOK / 256, 256, 0, stream>>>(topi, offs, pos, tlist, slotof);
  gemm_kernel<64, 32, false, true, 1><<<dim3(FFD / 128, NTOK / 64, NEXP), 256, 0, stream>>>(
      x2h, nullptr, w1t, nullptr, e_b1, hbuf, nullptr, NTOK, FFD, DIMc, tlist, cnt, offs);
  gemm_kernel<64, 32, false, false, 2><<<dim3(DIMc / 128, NTOK / 64, NEXP), 256, 0, stream>>>(
      hbuf, nullptr, w2t, nullptr, e_b2, eo, nullptr, NTOK, DIMc, FFD, nullptr, cnt, offs);
  final_kernel<<<NTOK, 256, 0, stream>>>(x2, eo, slotof, topwp, ln3_g, ln3_b, (float*)d_out);
}

// Round 15
// 1149.889 us; speedup vs baseline: 1.0486x; 1.0486x over previous
//
#include <hip/hip_runtime.h>

typedef unsigned short u16;
typedef unsigned int   u32;
typedef __bf16    bf16x8 __attribute__((ext_vector_type(8)));
typedef _Float16  f16x8  __attribute__((ext_vector_type(8)));
typedef _Float16  f16x4  __attribute__((ext_vector_type(4)));
typedef __fp16    fp16x2 __attribute__((ext_vector_type(2)));
typedef float     f32x4  __attribute__((ext_vector_type(4)));
typedef u16       u16x4  __attribute__((ext_vector_type(4)));

#define DEV static __device__ __forceinline__

#if __has_builtin(__builtin_amdgcn_mfma_f32_16x16x16f16)
#define HAVE_MFMA16 1
#else
#define HAVE_MFMA16 0
#endif

constexpr int DIMc  = 1024;
constexpr int NHEAD = 16;
constexpr int HDM   = 64;
constexpr int SLENc = 2048;
constexpr int NBAT  = 2;
constexpr int NTOK  = NBAT * SLENc;     // 4096
constexpr int FFD   = 4096;
constexpr int NEXP  = 8;
constexpr int NSLOT = 2 * NTOK;         // 8192
constexpr long TD   = (long)NTOK * DIMc;
constexpr float RSC = 2048.0f;          // residual scale 2^11
constexpr float RSCI = 1.0f / 2048.0f;
constexpr float LOG2E = 1.4426950408889634f;

DEV u16 f2bf(float f) {
  u32 u = __float_as_uint(f);
  u += 0x7fffu + ((u >> 16) & 1u);
  return (u16)(u >> 16);
}
DEV float bf2f(u16 h) { return __uint_as_float(((u32)h) << 16); }
DEV float h2f(u16 u) { union { _Float16 h; u16 u_; } x; x.u_ = u; return (float)x.h; }

// f32 -> f16 high + scaled residual (v ~= h + r/2048, rel err ~2^-22)
DEV void split2v(float v, u16& h, u16& r) {
  _Float16 hh = (_Float16)v;
  float rf = (v - (float)hh) * RSC;
  union { _Float16 h_; u16 u_; } a, b;
  a.h_ = hh; b.h_ = (_Float16)rf;
  h = a.u_; r = b.u_;
}

DEV u32 pkrtz(float a, float b) {
  union { fp16x2 v; u32 u; } x;
  x.v = __builtin_amdgcn_cvt_pkrtz(a, b);
  return x.u;
}

DEV f16x4 mk4(u32 lo, u32 hi) {
  union { u32 u[2]; f16x4 v; } x;
  x.u[0] = lo; x.u[1] = hi;
  return x.v;
}

DEV void async16(const void* g, void* l) {
  __builtin_amdgcn_global_load_lds((const u32*)g, (u32*)l, 16, 0, 0);
}

DEV f32x4 mfma_bf(bf16x8 a, bf16x8 b, f32x4 c) {
  return __builtin_amdgcn_mfma_f32_16x16x32_bf16(a, b, c, 0, 0, 0);
}
DEV f32x4 mfma_h(f16x8 a, f16x8 b, f32x4 c) {
  return __builtin_amdgcn_mfma_f32_16x16x32_f16(a, b, c, 0, 0, 0);
}
#if HAVE_MFMA16
DEV f32x4 mfma16h(f16x4 a, f16x4 b, f32x4 c) {
  return __builtin_amdgcn_mfma_f32_16x16x16f16(a, b, c, 0, 0, 0);
}
#endif

// swizzled fragment read from a [64][64] u16 LDS tile (rows 128B, 16B blocks XOR'd by row&7)
DEV f16x8 ldfragh(const u16 (*T)[64], int row, int blk) {
  return *(const f16x8*)((const u16*)T + row * 64 + ((blk ^ (row & 7)) * 8));
}
// 8B V-fragment for 16x16x16 PV: elems k' = kc*4..+3 of k-block kn, row d
DEV f16x4 ldVfrag4(const u16 (*T)[64], int row, int kn, int kc) {
  const int blk = kn * 2 + (kc >> 1);
  const u16* p = (const u16*)T + row * 64 + ((blk ^ (row & 7)) * 8) + (kc & 1) * 4;
  return *(const f16x4*)p;
}

// fast GELU (tanh form): max abs err ~1e-3, below bf16 storage noise of h
DEV float gelu_fast(float v) {
  float arg = v * fmaf(0.044715f * v, v, 1.0f) * 0.7978845608028654f;
  return v / (1.0f + __expf(-2.0f * arg));
}

// ---------------- elementwise f32 -> 2-way f16 split ----------------
__global__ __launch_bounds__(256) void split2_kernel(
    const float* __restrict__ x, u16* __restrict__ o0, u16* __restrict__ o1, long n) {
  long i = ((long)blockIdx.x * 256 + threadIdx.x) * 4;
  if (i >= n) return;
  f32x4 v = *(const f32x4*)(x + i);
  u16x4 h, r;
#pragma unroll
  for (int j = 0; j < 4; ++j) { u16 a, b; split2v(v[j], a, b); h[j] = a; r[j] = b; }
  *(u16x4*)(o0 + i) = h;
  *(u16x4*)(o1 + i) = r;
}

// ---------------- weight transpose + f16 2-split (W[R][C] -> Wt[C][R]) ----------
__global__ __launch_bounds__(256) void wsplit2_kernel(
    const float* __restrict__ W, u16* __restrict__ t0, u16* __restrict__ t1, int R, int C) {
  __shared__ alignas(16) float tile[32][33];
  const long base = (long)blockIdx.z * R * C;
  const int c0 = blockIdx.x * 32, r0 = blockIdx.y * 32;
  const int tx = threadIdx.x & 31, ty = threadIdx.x >> 5;
#pragma unroll
  for (int i = 0; i < 32; i += 8)
    tile[ty + i][tx] = W[base + (long)(r0 + ty + i) * C + (c0 + tx)];
  __syncthreads();
#pragma unroll
  for (int i = 0; i < 32; i += 8) {
    float v = tile[tx][ty + i];
    long oidx = base + (long)(c0 + ty + i) * R + (r0 + tx);
    u16 a, b; split2v(v, a, b);
    t0[oidx] = a; t1[oidx] = b;
  }
}

// ---------------- weight transpose -> single bf16 plane (MoE experts) ----------
__global__ __launch_bounds__(256) void wsplit1_kernel(
    const float* __restrict__ W, u16* __restrict__ t0, int R, int C) {
  __shared__ alignas(16) float tile[32][33];
  const long base = (long)blockIdx.z * R * C;
  const int c0 = blockIdx.x * 32, r0 = blockIdx.y * 32;
  const int tx = threadIdx.x & 31, ty = threadIdx.x >> 5;
#pragma unroll
  for (int i = 0; i < 32; i += 8)
    tile[ty + i][tx] = W[base + (long)(r0 + ty + i) * C + (c0 + tx)];
  __syncthreads();
#pragma unroll
  for (int i = 0; i < 32; i += 8) {
    long oidx = base + (long)(c0 + ty + i) * R + (r0 + tx);
    t0[oidx] = f2bf(tile[tx][ty + i]);
  }
}

// ---------------- bias concat: [bq|bk|bv] and [bk_c|bv_c] ----------------
__global__ __launch_bounds__(256) void biascat_kernel(
    const float* __restrict__ q, const float* __restrict__ k, const float* __restrict__ v,
    const float* __restrict__ ck, const float* __restrict__ cv,
    float* __restrict__ qkvb, float* __restrict__ kvb) {
  int i = blockIdx.x * 256 + threadIdx.x;
  if (i < 1024) qkvb[i] = q[i];
  else if (i < 2048) qkvb[i] = k[i - 1024];
  else if (i < 3072) qkvb[i] = v[i - 2048];
  else if (i < 4096) kvb[i - 3072] = ck[i - 3072];
  else if (i < 5120) kvb[i - 3072] = cv[i - 4096];
}

// ---------------- V transpose from split planes: V[t][ld] -> Vt[bh][d][s] ------
__global__ __launch_bounds__(256) void vtrans2_kernel(
    const u16* __restrict__ vh, const u16* __restrict__ vr, int ld,
    u16* __restrict__ t0, u16* __restrict__ t1) {
  __shared__ alignas(16) float tile[32][33];
  const int bh = blockIdx.z, b = bh >> 4, h = bh & 15;
  const int s0 = blockIdx.x * 32, d0 = blockIdx.y * 32;
  const int tx = threadIdx.x & 31, ty = threadIdx.x >> 5;
#pragma unroll
  for (int i = 0; i < 32; i += 8) {
    long idx = (long)(b * SLENc + s0 + ty + i) * ld + h * HDM + d0 + tx;
    tile[ty + i][tx] = h2f(vh[idx]) + h2f(vr[idx]) * RSCI;
  }
  __syncthreads();
#pragma unroll
  for (int i = 0; i < 32; i += 8) {
    float v = tile[tx][ty + i];
    long o = ((long)bh * HDM + d0 + ty + i) * SLENc + s0 + tx;
    u16 a, b_; split2v(v, a, b_);
    t0[o] = a; t1[o] = b_;
  }
}

// ---------------- GEMM: C[M][N] = A[M][K] @ Bt[N][K]^T (+bias, epilogue) --------
// MT: M-tile (64 or 128). N-tile fixed 128. SPLIT: f16 2-way split (3 mfma terms).
// BK=32: linear LDS, double-buffered prefetch pipeline (T3-min).
// EPI 0: f32 out; 1: gelu->bf16; 2: ->bf16; 3: f16 2-split planes (Cout,C1)
template<int MT, int BK, bool SPLIT, bool GATHER, int EPI>
__global__ __launch_bounds__(256) void gemm_kernel(
    const u16* __restrict__ A0, const u16* __restrict__ A1,
    const u16* __restrict__ B0, const u16* __restrict__ B1,
    const float* __restrict__ bias, void* __restrict__ Cout, u16* __restrict__ C1,
    int M, int N, int Kd,
    const int* __restrict__ tlist, const int* __restrict__ cnts, const int* __restrict__ offs) {
  constexpr int NP   = SPLIT ? 2 : 1;
  constexpr int NBUF = (BK == 32) ? 2 : 1;  // pipeline only BK=32
  constexpr int RPC  = 512 / BK;            // rows per 1KB staging chunk
  constexpr int ACH  = (MT / RPC) / 4;      // a-chunks per wave
  constexpr int BCH  = (128 / RPC) / 4;     // b-chunks per wave
  constexpr int MREP = MT / 32;             // m-fragments per wave
  constexpr int WRS  = MT / 2;              // per-wave row span
  __shared__ alignas(16) u16 As[NBUF][NP][MT * BK];
  __shared__ alignas(16) u16 Bs[NBUF][NP][128 * BK];

  const int e   = blockIdx.z;
  const int cnt = cnts ? cnts[e] : M;
  const int off = offs ? offs[e] : 0;
  const int m0  = blockIdx.y * MT;
  if (m0 >= cnt) return;
  const int n0  = blockIdx.x * 128;

  const int tid = threadIdx.x;
  const int lane = tid & 63, wid = tid >> 6;
  const int fr = lane & 15, kc = lane >> 4;
  const int wr = wid >> 1, wc = wid & 1;

  const long boff = (long)e * N * Kd;

  int srow, kseg8;
  if constexpr (BK == 32) { srow = lane >> 2; kseg8 = lane & 3; }
  else                    { srow = lane >> 3; kseg8 = (lane & 7) ^ (srow & 7); }

  long aoff[ACH], boff_[BCH];
#pragma unroll
  for (int c = 0; c < ACH; ++c) {
    const int row = (wid * ACH + c) * RPC + srow;
    long ar;
    if (GATHER) {
      int idx = m0 + row; if (idx >= cnt) idx = cnt - 1;
      ar = tlist[off + idx];
    } else {
      ar = (long)(off + m0 + row);
    }
    aoff[c] = ar * Kd + kseg8 * 8;
  }
#pragma unroll
  for (int c = 0; c < BCH; ++c) {
    const int row = (wid * BCH + c) * RPC + srow;
    boff_[c] = boff + (long)(n0 + row) * Kd + kseg8 * 8;
  }

  f32x4 acc[MREP][4], acc1[MREP][4];
#pragma unroll
  for (int m = 0; m < MREP; ++m)
#pragma unroll
    for (int n = 0; n < 4; ++n) { acc[m][n] = f32x4{0.f,0.f,0.f,0.f}; acc1[m][n] = f32x4{0.f,0.f,0.f,0.f}; }

  auto stage = [&](int kt, int bufi) {
    const int k0 = kt * BK;
#pragma unroll
    for (int c = 0; c < ACH; ++c) {
      const int chunk = wid * ACH + c;
      async16(A0 + aoff[c] + k0, &As[bufi][0][chunk * 512]);
      if constexpr (SPLIT) async16(A1 + aoff[c] + k0, &As[bufi][1][chunk * 512]);
    }
#pragma unroll
    for (int c = 0; c < BCH; ++c) {
      const int chunk = wid * BCH + c;
      async16(B0 + boff_[c] + k0, &Bs[bufi][0][chunk * 512]);
      if constexpr (SPLIT) async16(B1 + boff_[c] + k0, &Bs[bufi][1][chunk * 512]);
    }
  };

  auto compute = [&](int bufi) {
    if constexpr (BK == 32) {
      if constexpr (SPLIT) {
        f16x8 a0[MREP], a1[MREP];
#pragma unroll
        for (int m = 0; m < MREP; ++m) {
          const int idx = (wr * WRS + m * 16 + fr) * 32 + kc * 8;
          a0[m] = *(const f16x8*)&As[bufi][0][idx];
          a1[m] = *(const f16x8*)&As[bufi][1][idx];
        }
#pragma unroll
        for (int n = 0; n < 4; ++n) {
          const int idx = (wc * 64 + n * 16 + fr) * 32 + kc * 8;
          f16x8 b0 = *(const f16x8*)&Bs[bufi][0][idx];
          f16x8 b1 = *(const f16x8*)&Bs[bufi][1][idx];
#pragma unroll
          for (int m = 0; m < MREP; ++m) {
            acc[m][n]  = mfma_h(a0[m], b0, acc[m][n]);
            acc1[m][n] = mfma_h(a0[m], b1, acc1[m][n]);
            acc1[m][n] = mfma_h(a1[m], b0, acc1[m][n]);
          }
        }
      } else {
        bf16x8 a0[MREP];
#pragma unroll
        for (int m = 0; m < MREP; ++m)
          a0[m] = *(const bf16x8*)&As[bufi][0][(wr * WRS + m * 16 + fr) * 32 + kc * 8];
#pragma unroll
        for (int n = 0; n < 4; ++n) {
          bf16x8 b0 = *(const bf16x8*)&Bs[bufi][0][(wc * 64 + n * 16 + fr) * 32 + kc * 8];
#pragma unroll
          for (int m = 0; m < MREP; ++m)
            acc[m][n] = mfma_bf(a0[m], b0, acc[m][n]);
        }
      }
    } else {
      // BK=64, bf16 only. XOR-swizzled reads: blk' = blk ^ (row&7); row&7 == fr&7.
#pragma unroll
      for (int ksub = 0; ksub < 2; ++ksub) {
        bf16x8 a0[MREP];
#pragma unroll
        for (int m = 0; m < MREP; ++m) {
          const int row = wr * WRS + m * 16 + fr;
          a0[m] = *(const bf16x8*)&As[0][0][row * 64 + (((ksub << 2) | kc) ^ (fr & 7)) * 8];
        }
#pragma unroll
        for (int n = 0; n < 4; ++n) {
          const int row = wc * 64 + n * 16 + fr;
          bf16x8 b0 = *(const bf16x8*)&Bs[0][0][row * 64 + (((ksub << 2) | kc) ^ (fr & 7)) * 8];
#pragma unroll
          for (int m = 0; m < MREP; ++m)
            acc[m][n] = mfma_bf(a0[m], b0, acc[m][n]);
        }
      }
    }
  };

  const int NK = Kd / BK;
  if constexpr (BK == 32) {
    // T3-min pipelined double buffer: prefetch kt+1 before computing kt.
    stage(0, 0);
    int cur = 0;
    for (int kt = 0; kt < NK; ++kt) {
      __syncthreads();                       // drains vmcnt -> tile kt ready; all waves done with other buf
      if (kt + 1 < NK) stage(kt + 1, cur ^ 1);
      compute(cur);
      cur ^= 1;
    }
  } else {
    for (int kt = 0; kt < NK; ++kt) {
      __syncthreads();
      stage(kt, 0);
      __syncthreads();
      compute(0);
    }
  }

  const float* bvec = bias + (long)e * N;
#pragma unroll
  for (int m = 0; m < MREP; ++m) {
#pragma unroll
    for (int j = 0; j < 4; ++j) {
      const int r = m0 + wr * WRS + m * 16 + kc * 4 + j;
      if (r >= cnt) continue;
      const long orow = (long)(off + r) * N;
#pragma unroll
      for (int n = 0; n < 4; ++n) {
        const int col = n0 + wc * 64 + n * 16 + fr;
        float v = acc[m][n][j];
        if constexpr (SPLIT) v += acc1[m][n][j] * RSCI;
        v += bvec[col];
        if constexpr (EPI == 0) {
          ((float*)Cout)[orow + col] = v;
        } else if constexpr (EPI == 1) {
          ((u16*)Cout)[orow + col] = f2bf(gelu_fast(v));
        } else if constexpr (EPI == 2) {
          ((u16*)Cout)[orow + col] = f2bf(v);
        } else {
          u16 a_, b_; split2v(v, a_, b_);
          ((u16*)Cout)[orow + col] = a_;
          C1[orow + col] = b_;
        }
      }
    }
  }
}

// ---------------- MFMA flash attention, f16 2-split, QBLK=128 / 8 waves --------
#if !HAVE_MFMA16
DEV f16x8 gather_fragh(u32 a0, u32 a1, u32 b0, u32 b1, int lane) {
  const int kc = lane >> 4;
  const int base = (lane & 15) + ((kc & 1) << 5);
  union { u32 u[4]; f16x8 v; } r;
  u32 s00 = (u32)__shfl((int)a0, base, 64);
  u32 s01 = (u32)__shfl((int)a1, base, 64);
  u32 s10 = (u32)__shfl((int)b0, base, 64);
  u32 s11 = (u32)__shfl((int)b1, base, 64);
  u32 t00 = (u32)__shfl((int)a0, base + 16, 64);
  u32 t01 = (u32)__shfl((int)a1, base + 16, 64);
  u32 t10 = (u32)__shfl((int)b0, base + 16, 64);
  u32 t11 = (u32)__shfl((int)b1, base + 16, 64);
  const bool hi = (kc >> 1) != 0;
  r.u[0] = hi ? s10 : s00;
  r.u[1] = hi ? s11 : s01;
  r.u[2] = hi ? t10 : t00;
  r.u[3] = hi ? t11 : t01;
  return r.v;
}
#endif

template<bool CAUSAL>
__global__ __launch_bounds__(512, 4) void attn2_kernel(
    const u16* __restrict__ Qh, const u16* __restrict__ Qr, int qld,
    const u16* __restrict__ Kh, const u16* __restrict__ Kr, int kld,
    const u16* __restrict__ Vh, const u16* __restrict__ Vr,
    u16* __restrict__ OH, u16* __restrict__ OR) {
  __shared__ alignas(16) u16 KQs[2][2][64][64];   // [buf][plane][row][col]
  __shared__ alignas(16) u16 Vts[2][2][64][64];

  // LPT schedule for causal: heavy blocks (large qt => most k-tiles) launch first
  const int qt = CAUSAL ? ((int)gridDim.x - 1 - (int)blockIdx.x) : (int)blockIdx.x;
  const int h = blockIdx.y, b = blockIdx.z;
  const int tid = threadIdx.x, lane = tid & 63, w = tid >> 6;   // w in 0..7
  const int wq = w >> 2, wl = w & 3;          // q-half, role within half
  const int fr = lane & 15, kc = lane >> 4;
  const int q0 = qt * 128;
  const int qrow = wq * 64 + wl * 16 + fr;    // q row within block (0..127)
  const int qglob = q0 + qrow;                // global q row (causal mask RHS)
  const long qbase = (long)(b * SLENc) * qld + h * HDM;
  const long kbase = (long)(b * SLENc) * kld + h * HDM;
  const long obase = (long)(b * SLENc) * DIMc + h * HDM;
  const long vtbase = (long)(b * NHEAD + h) * HDM * SLENc;
  const int r = lane >> 3, blk = (lane & 7) ^ r;

  auto stageKV = [&](int kt, int bufi) {
    // 8 waves: wave w loads rows 8w..8w+7 of the 64-row K and V tiles
#pragma unroll
    for (int p = 0; p < 2; ++p) {
      const u16* gp = (p == 0 ? Kh : Kr);
      async16(gp + kbase + (long)(kt * 64 + 8 * w + r) * kld + blk * 8, &KQs[bufi][p][8 * w][0]);
    }
    const long vrow = vtbase + kt * 64;
#pragma unroll
    for (int p = 0; p < 2; ++p) {
      const u16* gp = (p == 0 ? Vh : Vr);
      async16(gp + vrow + (long)(8 * w + r) * SLENc + blk * 8, &Vts[bufi][p][8 * w][0]);
    }
  };

  // ---- prologue: stage 128 Q rows (half0 -> KQs[0], half1 -> Vts[0]) ----
#pragma unroll
  for (int hh = 0; hh < 2; ++hh) {
#pragma unroll
    for (int p = 0; p < 2; ++p) {
      const u16* gp = (p == 0 ? Qh : Qr);
      u16* dst = hh == 0 ? &KQs[0][p][8 * w][0] : &Vts[0][p][8 * w][0];
      async16(gp + qbase + (long)(q0 + hh * 64 + 8 * w + r) * qld + blk * 8, dst);
    }
  }
  __syncthreads();
  f16x8 qf0[2], qf1[2];
  {
    const u16 (*Q0)[64] = (wq == 0) ? KQs[0][0] : Vts[0][0];
    const u16 (*Q1)[64] = (wq == 0) ? KQs[0][1] : Vts[0][1];
#pragma unroll
    for (int s = 0; s < 2; ++s) {
      qf0[s] = ldfragh(Q0, wl * 16 + fr, s * 4 + kc);
      qf1[s] = ldfragh(Q1, wl * 16 + fr, s * 4 + kc);
    }
  }
  // prefetch K/V tile 0 into buf1 (doesn't touch buf0 just read)
  stageKV(0, 1);

  f32x4 accO0[4], accO1[4];
#pragma unroll
  for (int dn = 0; dn < 4; ++dn) { accO0[dn] = f32x4{0.f,0.f,0.f,0.f}; accO1[dn] = f32x4{0.f,0.f,0.f,0.f}; }
  float m_ = -3e38f, l_ = 0.f;   // m_ in log2 domain

  const int nkt = CAUSAL ? (2 * qt + 2) : (SLENc / 64);
  int cur = 1;
  for (int kt = 0; kt < nkt; ++kt) {
    __syncthreads();                        // tile kt landed in bufs[cur]; all waves done with bufs[cur^1]
    if (kt + 1 < nkt) stageKV(kt + 1, cur ^ 1);

    // ---- QK^T (swapped): sc at (k = kn*16 + kc*4 + j, q = fr) ----
    f32x4 sc0[4], sc1[4];
#pragma unroll
    for (int kn = 0; kn < 4; ++kn) { sc0[kn] = f32x4{0.f,0.f,0.f,0.f}; sc1[kn] = f32x4{0.f,0.f,0.f,0.f}; }
    __builtin_amdgcn_s_setprio(1);
#pragma unroll
    for (int kn = 0; kn < 4; ++kn)
#pragma unroll
      for (int s = 0; s < 2; ++s) {
        f16x8 ah = ldfragh(KQs[cur][0], kn * 16 + fr, s * 4 + kc);
        f16x8 ar = ldfragh(KQs[cur][1], kn * 16 + fr, s * 4 + kc);
        sc0[kn] = mfma_h(ah, qf0[s], sc0[kn]);
        sc1[kn] = mfma_h(ah, qf1[s], sc1[kn]);
        sc1[kn] = mfma_h(ar, qf0[s], sc1[kn]);
      }
    __builtin_amdgcn_s_setprio(0);

    // ---- online softmax in log2 domain (per-lane row q = fr) ----
    constexpr float SCL = 0.125f * LOG2E, SCL2 = 0.125f * RSCI * LOG2E;
    float p_[4][4];
    float mx = -3e38f;
#pragma unroll
    for (int kn = 0; kn < 4; ++kn)
#pragma unroll
      for (int j = 0; j < 4; ++j) {
        float sv = fmaf(sc0[kn][j], SCL, sc1[kn][j] * SCL2);
        if (CAUSAL) {
          if (kt * 64 + kn * 16 + kc * 4 + j > qglob) sv = -3e38f;  // absolute key idx vs global q idx
        }
        p_[kn][j] = sv;
        mx = fmaxf(mx, sv);
      }
    mx = fmaxf(mx, __shfl_xor(mx, 16, 64));
    mx = fmaxf(mx, __shfl_xor(mx, 32, 64));
    // T13 defer-rescale: skip when max growth fits 2^11.54 (= e^8) headroom
    if (!__all(mx <= m_ + 11.5415603f)) {
      const float mn = fmaxf(m_, mx);
      const float corr = exp2f(m_ - mn);
      m_ = mn;
      l_ *= corr;
#pragma unroll
      for (int dn = 0; dn < 4; ++dn) { accO0[dn] *= corr; accO1[dn] *= corr; }
    }
    float rs = 0.f;
#pragma unroll
    for (int kn = 0; kn < 4; ++kn)
#pragma unroll
      for (int j = 0; j < 4; ++j) {
        float p = exp2f(p_[kn][j] - m_);
        p_[kn][j] = p;
        rs += p;
      }
    rs += __shfl_xor(rs, 16, 64);
    rs += __shfl_xor(rs, 32, 64);
    l_ += rs;

#if HAVE_MFMA16
    // ---- PV via 16x16x16 mfma: B-frag (P column q=fr, k=kc*4+j) is lane-local ----
#pragma unroll
    for (int kn = 0; kn < 4; ++kn) {
      u32 hp0 = pkrtz(p_[kn][0], p_[kn][1]);
      u32 hp1 = pkrtz(p_[kn][2], p_[kn][3]);
      float h0 = h2f((u16)hp0), h1 = h2f((u16)(hp0 >> 16));
      float h2_ = h2f((u16)hp1), h3 = h2f((u16)(hp1 >> 16));
      u32 rp0 = pkrtz((p_[kn][0] - h0) * RSC, (p_[kn][1] - h1) * RSC);
      u32 rp1 = pkrtz((p_[kn][2] - h2_) * RSC, (p_[kn][3] - h3) * RSC);
      f16x4 ph = mk4(hp0, hp1), pr = mk4(rp0, rp1);
      __builtin_amdgcn_s_setprio(1);
#pragma unroll
      for (int dn = 0; dn < 4; ++dn) {
        f16x4 vh = ldVfrag4(Vts[cur][0], dn * 16 + fr, kn, kc);
        f16x4 vr = ldVfrag4(Vts[cur][1], dn * 16 + fr, kn, kc);
        accO0[dn] = mfma16h(vh, ph, accO0[dn]);
        accO1[dn] = mfma16h(vh, pr, accO1[dn]);
        accO1[dn] = mfma16h(vr, ph, accO1[dn]);
      }
      __builtin_amdgcn_s_setprio(0);
    }
#else
    // ---- fallback: split P, redistribute via lane gathers, 16x16x32 PV ----
    u32 hpk[4][2], rpk[4][2];
#pragma unroll
    for (int kn = 0; kn < 4; ++kn)
#pragma unroll
      for (int jp = 0; jp < 2; ++jp) {
        float p0 = p_[kn][2 * jp], p1 = p_[kn][2 * jp + 1];
        u32 hp = pkrtz(p0, p1);
        float h0 = h2f((u16)hp), h1 = h2f((u16)(hp >> 16));
        u32 rp = pkrtz((p0 - h0) * RSC, (p1 - h1) * RSC);
        hpk[kn][jp] = hp;
        rpk[kn][jp] = rp;
      }
#pragma unroll
    for (int s = 0; s < 2; ++s) {
      f16x8 ph = gather_fragh(hpk[2 * s][0], hpk[2 * s][1], hpk[2 * s + 1][0], hpk[2 * s + 1][1], lane);
      f16x8 pr = gather_fragh(rpk[2 * s][0], rpk[2 * s][1], rpk[2 * s + 1][0], rpk[2 * s + 1][1], lane);
      __builtin_amdgcn_s_setprio(1);
#pragma unroll
      for (int dn = 0; dn < 4; ++dn) {
        f16x8 vh = ldfragh(Vts[cur][0], dn * 16 + fr, s * 4 + kc);
        f16x8 vr = ldfragh(Vts[cur][1], dn * 16 + fr, s * 4 + kc);
        accO0[dn] = mfma_h(vh, ph, accO0[dn]);
        accO1[dn] = mfma_h(vh, pr, accO1[dn]);
        accO1[dn] = mfma_h(vr, ph, accO1[dn]);
      }
      __builtin_amdgcn_s_setprio(0);
    }
#endif
    cur ^= 1;
  }

  const float inv = 1.0f / l_;
#pragma unroll
  for (int dn = 0; dn < 4; ++dn) {
    u16x4 hv, rv;
#pragma unroll
    for (int j = 0; j < 4; ++j) {
      float o = (accO0[dn][j] + accO1[dn][j] * RSCI) * inv;
      u16 a_, b_; split2v(o, a_, b_);
      hv[j] = a_; rv[j] = b_;
    }
    const long oidx = obase + (long)(q0 + qrow) * DIMc + dn * 16 + kc * 4;
    *(u16x4*)&OH[oidx] = hv;
    *(u16x4*)&OR[oidx] = rv;
  }
}

// ---------------- residual + layernorm (+ optional split outputs) ----------------
template<int NS>
__global__ __launch_bounds__(256) void resln_kernel(
    const float* __restrict__ resid, const float* __restrict__ proj,
    const float* __restrict__ gam, const float* __restrict__ bet,
    float* __restrict__ yout, u16* __restrict__ s0, u16* __restrict__ s1) {
  __shared__ float red[4];
  const int t = blockIdx.x, tid = threadIdx.x;
  const long base = (long)t * DIMc;
  float v[4];
#pragma unroll
  for (int i = 0; i < 4; ++i) {
    int d = tid + i * 256;
    v[i] = resid[base + d] + proj[base + d];
  }
  float s = v[0] + v[1] + v[2] + v[3];
#pragma unroll
  for (int o = 32; o; o >>= 1) s += __shfl_xor(s, o, 64);
  if ((tid & 63) == 0) red[tid >> 6] = s;
  __syncthreads();
  const float mean = (red[0] + red[1] + red[2] + red[3]) * (1.0f / DIMc);
  __syncthreads();
  float q = 0.f;
#pragma unroll
  for (int i = 0; i < 4; ++i) { float d_ = v[i] - mean; q += d_ * d_; }
#pragma unroll
  for (int o = 32; o; o >>= 1) q += __shfl_xor(q, o, 64);
  if ((tid & 63) == 0) red[tid >> 6] = q;
  __syncthreads();
  const float var = (red[0] + red[1] + red[2] + red[3]) * (1.0f / DIMc);
  const float inv = rsqrtf(var + 1e-5f);
#pragma unroll
  for (int i = 0; i < 4; ++i) {
    int d = tid + i * 256;
    float y = (v[i] - mean) * inv * gam[d] + bet[d];
    yout[base + d] = y;
    if constexpr (NS == 1) s0[base + d] = f2bf(y);
    if constexpr (NS == 2) {
      u16 a, b; split2v(y, a, b);
      s0[base + d] = a; s1[base + d] = b;
    }
  }
}

// ---------------- residual + LN2 + fused router (logits, top-2, counts) --------
__global__ __launch_bounds__(256) void resln_router_kernel(
    const float* __restrict__ resid, const float* __restrict__ proj,
    const float* __restrict__ gam, const float* __restrict__ bet,
    const float* __restrict__ rw, const float* __restrict__ rb,
    float* __restrict__ yout, u16* __restrict__ s0,
    int* __restrict__ topi, float* __restrict__ topw, int* __restrict__ cnt) {
  __shared__ float red[4];
  __shared__ float rpart[4][8];
  const int t = blockIdx.x, tid = threadIdx.x;
  const int lane = tid & 63, wv = tid >> 6;
  const long base = (long)t * DIMc;
  float v[4];
#pragma unroll
  for (int i = 0; i < 4; ++i) {
    int d = tid + i * 256;
    v[i] = resid[base + d] + proj[base + d];
  }
  float s = v[0] + v[1] + v[2] + v[3];
#pragma unroll
  for (int o = 32; o; o >>= 1) s += __shfl_xor(s, o, 64);
  if (lane == 0) red[wv] = s;
  __syncthreads();
  const float mean = (red[0] + red[1] + red[2] + red[3]) * (1.0f / DIMc);
  __syncthreads();
  float q = 0.f;
#pragma unroll
  for (int i = 0; i < 4; ++i) { float d_ = v[i] - mean; q += d_ * d_; }
#pragma unroll
  for (int o = 32; o; o >>= 1) q += __shfl_xor(q, o, 64);
  if (lane == 0) red[wv] = q;
  __syncthreads();
  const float var = (red[0] + red[1] + red[2] + red[3]) * (1.0f / DIMc);
  const float inv = rsqrtf(var + 1e-5f);
  float part[8] = {};
#pragma unroll
  for (int i = 0; i < 4; ++i) {
    int d = tid + i * 256;
    float y = (v[i] - mean) * inv * gam[d] + bet[d];
    yout[base + d] = y;
    s0[base + d] = f2bf(y);
    const f32x4* wp = (const f32x4*)&rw[d * 8];
    f32x4 w0 = wp[0], w1 = wp[1];
    part[0] += y * w0[0]; part[1] += y * w0[1]; part[2] += y * w0[2]; part[3] += y * w0[3];
    part[4] += y * w1[0]; part[5] += y * w1[1]; part[6] += y * w1[2]; part[7] += y * w1[3];
  }
#pragma unroll
  for (int o = 32; o; o >>= 1)
#pragma unroll
    for (int e = 0; e < 8; ++e) part[e] += __shfl_xor(part[e], o, 64);
  if (lane == 0)
#pragma unroll
    for (int e = 0; e < 8; ++e) rpart[wv][e] = part[e];
  __syncthreads();
  if (tid == 0) {
    float lg[8];
#pragma unroll
    for (int e = 0; e < 8; ++e)
      lg[e] = rpart[0][e] + rpart[1][e] + rpart[2][e] + rpart[3][e] + rb[e];
    int i1 = 0;
#pragma unroll
    for (int e = 1; e < 8; ++e) if (lg[e] > lg[i1]) i1 = e;
    int i2 = (i1 == 0) ? 1 : 0;
#pragma unroll
    for (int e = 0; e < 8; ++e) if (e != i1 && lg[e] > lg[i2]) i2 = e;
    float mx = lg[i1], ps = 0.f, p[8];
#pragma unroll
    for (int e = 0; e < 8; ++e) { p[e] = __expf(lg[e] - mx); ps += p[e]; }
    float p1 = p[i1] / ps, p2 = p[i2] / ps;
    float e2 = __expf(p2 - p1);
    float w1 = 1.0f / (1.0f + e2);
    topi[t * 2] = i1; topi[t * 2 + 1] = i2;
    topw[t * 2] = w1; topw[t * 2 + 1] = e2 * w1;
    atomicAdd(&cnt[i1], 1); atomicAdd(&cnt[i2], 1);
  }
}

__global__ void scan_kernel(const int* __restrict__ cnt, int* __restrict__ offs, int* __restrict__ pos) {
  if (threadIdx.x == 0) {
    int a = 0;
    for (int e = 0; e < NEXP; ++e) { offs[e] = a; a += cnt[e]; }
  }
  if (threadIdx.x < NEXP) pos[threadIdx.x] = 0;
}

__global__ __launch_bounds__(256) void fill_kernel(
    const int* __restrict__ topi, const int* __restrict__ offs, int* __restrict__ pos,
    int* __restrict__ tlist, int* __restrict__ slotof) {
  int t = blockIdx.x * 256 + threadIdx.x;
  if (t >= NTOK) return;
#pragma unroll
  for (int k = 0; k < 2; ++k) {
    int e = topi[t * 2 + k];
    int pp = atomicAdd(&pos[e], 1);
    int s = offs[e] + pp;
    tlist[s] = t;
    slotof[t * 2 + k] = s;
  }
}

// ---------------- final: combine experts + residual + LN3 -> f32 out ----------------
__global__ __launch_bounds__(256) void final_kernel(
    const float* __restrict__ x2, const u16* __restrict__ eo,
    const int* __restrict__ slotof, const float* __restrict__ topw,
    const float* __restrict__ gam, const float* __restrict__ bet, float* __restrict__ out) {
  __shared__ float red[4];
  const int t = blockIdx.x, tid = threadIdx.x;
  const long base = (long)t * DIMc;
  const int s0 = slotof[t * 2], s1 = slotof[t * 2 + 1];
  const float w0 = topw[t * 2], w1 = topw[t * 2 + 1];
  float v[4];
#pragma unroll
  for (int i = 0; i < 4; ++i) {
    int d = tid + i * 256;
    float moe = w0 * bf2f(eo[(long)s0 * DIMc + d]) + w1 * bf2f(eo[(long)s1 * DIMc + d]);
    v[i] = x2[base + d] + moe;
  }
  float s = v[0] + v[1] + v[2] + v[3];
#pragma unroll
  for (int o = 32; o; o >>= 1) s += __shfl_xor(s, o, 64);
  if ((tid & 63) == 0) red[tid >> 6] = s;
  __syncthreads();
  const float mean = (red[0] + red[1] + red[2] + red[3]) * (1.0f / DIMc);
  __syncthreads();
  float q = 0.f;
#pragma unroll
  for (int i = 0; i < 4; ++i) { float d_ = v[i] - mean; q += d_ * d_; }
#pragma unroll
  for (int o = 32; o; o >>= 1) q += __shfl_xor(q, o, 64);
  if ((tid & 63) == 0) red[tid >> 6] = q;
  __syncthreads();
  const float var = (red[0] + red[1] + red[2] + red[3]) * (1.0f / DIMc);
  const float inv = rsqrtf(var + 1e-5f);
#pragma unroll
  for (int i = 0; i < 4; ++i) {
    int d = tid + i * 256;
    out[base + d] = (v[i] - mean) * inv * gam[d] + bet[d];
  }
}

// ---------------- host orchestration ----------------
extern "C" void kernel_launch(void* const* d_in, const int* in_sizes, int n_in,
                              void* d_out, int out_size, void* d_ws, size_t ws_size,
                              hipStream_t stream) {
  (void)in_sizes; (void)n_in; (void)out_size; (void)ws_size;
  const float* x     = (const float*)d_in[0];
  const float* enc   = (const float*)d_in[1];
  const float* aw[8] = {(const float*)d_in[2],  (const float*)d_in[4],  (const float*)d_in[6],  (const float*)d_in[8],
                        (const float*)d_in[10], (const float*)d_in[12], (const float*)d_in[14], (const float*)d_in[16]};
  const float* ab[8] = {(const float*)d_in[3],  (const float*)d_in[5],  (const float*)d_in[7],  (const float*)d_in[9],
                        (const float*)d_in[11], (const float*)d_in[13], (const float*)d_in[15], (const float*)d_in[17]};
  const float* ln1_g = (const float*)d_in[18]; const float* ln1_b = (const float*)d_in[19];
  const float* ln2_g = (const float*)d_in[20]; const float* ln2_b = (const float*)d_in[21];
  const float* ln3_g = (const float*)d_in[22]; const float* ln3_b = (const float*)d_in[23];
  const float* rw    = (const float*)d_in[24]; const float* rb    = (const float*)d_in[25];
  const float* e_w1  = (const float*)d_in[26]; const float* e_b1  = (const float*)d_in[27];
  const float* e_w2  = (const float*)d_in[28]; const float* e_b2  = (const float*)d_in[29];

  char* basep = (char*)d_ws;
  size_t offb = 0;
  auto alloc = [&](size_t nbytes) -> void* {
    void* r = basep + offb;
    offb += (nbytes + 255) & ~(size_t)255;
    return r;
  };

  const size_t PLANE_BF = (size_t)TD * 2;   // 8 MB u16 plane
  const size_t PLANE_F  = (size_t)TD * 4;   // 16 MB f32 plane
  const size_t WPLANE   = (size_t)DIMc * DIMc * 2;  // 2 MB weight plane

  u16 *xs0 = (u16*)alloc(PLANE_BF), *xs1 = (u16*)alloc(PLANE_BF);
  u16 *es0 = (u16*)alloc(PLANE_BF), *es1 = (u16*)alloc(PLANE_BF);
  u16 *os0 = (u16*)alloc(PLANE_BF), *os1 = (u16*)alloc(PLANE_BF);
  u16 *wqkv0 = (u16*)alloc(3 * WPLANE), *wqkv1 = (u16*)alloc(3 * WPLANE);
  u16 *wkv0  = (u16*)alloc(2 * WPLANE), *wkv1  = (u16*)alloc(2 * WPLANE);
  u16 *wq0   = (u16*)alloc(WPLANE),     *wq1   = (u16*)alloc(WPLANE);
  u16 *wo10  = (u16*)alloc(WPLANE),     *wo11  = (u16*)alloc(WPLANE);
  u16 *wo20  = (u16*)alloc(WPLANE),     *wo21  = (u16*)alloc(WPLANE);
  u16* w1t = (u16*)alloc((size_t)NEXP * FFD * DIMc * 2);
  u16* w2t = (u16*)alloc((size_t)NEXP * DIMc * FFD * 2);
  u16 *QKVh = (u16*)alloc(3 * PLANE_BF), *QKVr = (u16*)alloc(3 * PLANE_BF);
  u16 *KVh  = (u16*)alloc(2 * PLANE_BF), *KVr  = (u16*)alloc(2 * PLANE_BF);
  u16 *Qch  = (u16*)alloc(PLANE_BF),     *Qcr  = (u16*)alloc(PLANE_BF);
  u16 *Vth  = (u16*)alloc(PLANE_BF),     *Vtr  = (u16*)alloc(PLANE_BF);
  float* qkvb = (float*)alloc(3072 * 4);
  float* kvb  = (float*)alloc(2048 * 4);
  float* aout = (float*)alloc(PLANE_F);
  float* x1   = (float*)alloc(PLANE_F);
  float* x2   = (float*)alloc(PLANE_F);
  u16*   x2h  = (u16*)alloc(PLANE_BF);
  u16*   hbuf = (u16*)alloc((size_t)(NSLOT + 128) * FFD * 2);
  u16*   eo   = (u16*)alloc((size_t)NSLOT * DIMc * 2);
  int*   topi   = (int*)alloc(NSLOT * 4);
  float* topwp  = (float*)alloc(NSLOT * 4);
  int*   tlist  = (int*)alloc(NSLOT * 4);
  int*   slotof = (int*)alloc(NSLOT * 4);
  int*   cnt    = (int*)alloc(NEXP * 4);
  int*   offs   = (int*)alloc(NEXP * 4);
  int*   pos    = (int*)alloc(NEXP * 4);

  (void)hipMemsetAsync(cnt, 0, NEXP * sizeof(int), stream);

  const int SB = (int)(TD / 4 / 256);
  split2_kernel<<<SB, 256, 0, stream>>>(x, xs0, xs1, TD);
  split2_kernel<<<SB, 256, 0, stream>>>(enc, es0, es1, TD);
  // stacked weight planes: self QKV rows 0..3071; cross KV rows 0..2047
  for (int s = 0; s < 3; ++s)
    wsplit2_kernel<<<dim3(32, 32, 1), 256, 0, stream>>>(aw[s], wqkv0 + (size_t)s * DIMc * DIMc, wqkv1 + (size_t)s * DIMc * DIMc, DIMc, DIMc);
  wsplit2_kernel<<<dim3(32, 32, 1), 256, 0, stream>>>(aw[5], wkv0, wkv1, DIMc, DIMc);
  wsplit2_kernel<<<dim3(32, 32, 1), 256, 0, stream>>>(aw[6], wkv0 + (size_t)DIMc * DIMc, wkv1 + (size_t)DIMc * DIMc, DIMc, DIMc);
  wsplit2_kernel<<<dim3(32, 32, 1), 256, 0, stream>>>(aw[4], wq0, wq1, DIMc, DIMc);
  wsplit2_kernel<<<dim3(32, 32, 1), 256, 0, stream>>>(aw[3], wo10, wo11, DIMc, DIMc);
  wsplit2_kernel<<<dim3(32, 32, 1), 256, 0, stream>>>(aw[7], wo20, wo21, DIMc, DIMc);
  wsplit1_kernel<<<dim3(FFD / 32, DIMc / 32, NEXP), 256, 0, stream>>>(e_w1, w1t, DIMc, FFD);
  wsplit1_kernel<<<dim3(DIMc / 32, FFD / 32, NEXP), 256, 0, stream>>>(e_w2, w2t, FFD, DIMc);
  biascat_kernel<<<20, 256, 0, stream>>>(ab[0], ab[1], ab[2], ab[5], ab[6], qkvb, kvb);

  const dim3 gproj(DIMc / 128, NTOK / 64, 1);        // MT=64
  const dim3 gqkv(3 * DIMc / 128, NTOK / 64, 1);     // MT=64
  const dim3 gkv(2 * DIMc / 128, NTOK / 64, 1);      // MT=64
  const dim3 gattn(SLENc / 128, NHEAD, NBAT);        // QBLK=128, 512 blocks
  const dim3 gvt(SLENc / 32, HDM / 32, NBAT * NHEAD);

  // ---- self-attention ----
  gemm_kernel<64, 32, true, false, 3><<<gqkv, 256, 0, stream>>>(xs0, xs1, wqkv0, wqkv1, qkvb, QKVh, QKVr, NTOK, 3 * DIMc, DIMc, nullptr, nullptr, nullptr);
  vtrans2_kernel<<<gvt, 256, 0, stream>>>(QKVh + 2048, QKVr + 2048, 3 * DIMc, Vth, Vtr);
  attn2_kernel<true><<<gattn, 512, 0, stream>>>(QKVh, QKVr, 3 * DIMc, QKVh + 1024, QKVr + 1024, 3 * DIMc, Vth, Vtr, os0, os1);
  gemm_kernel<64, 32, true, false, 0><<<gproj, 256, 0, stream>>>(os0, os1, wo10, wo11, ab[3], aout, nullptr, NTOK, DIMc, DIMc, nullptr, nullptr, nullptr);
  resln_kernel<2><<<NTOK, 256, 0, stream>>>(x, aout, ln1_g, ln1_b, x1, xs0, xs1);
  // ---- cross-attention ----
  gemm_kernel<64, 32, true, false, 3><<<gproj, 256, 0, stream>>>(xs0, xs1, wq0, wq1, ab[4], Qch, Qcr, NTOK, DIMc, DIMc, nullptr, nullptr, nullptr);
  gemm_kernel<64, 32, true, false, 3><<<gkv, 256, 0, stream>>>(es0, es1, wkv0, wkv1, kvb, KVh, KVr, NTOK, 2 * DIMc, DIMc, nullptr, nullptr, nullptr);
  vtrans2_kernel<<<gvt, 256, 0, stream>>>(KVh + 1024, KVr + 1024, 2 * DIMc, Vth, Vtr);
  attn2_kernel<false><<<gattn, 512, 0, stream>>>(Qch, Qcr, DIMc, KVh, KVr, 2 * DIMc, Vth, Vtr, os0, os1);
  gemm_kernel<64, 32, true, false, 0><<<gproj, 256, 0, stream>>>(os0, os1, wo20, wo21, ab[7], aout, nullptr, NTOK, DIMc, DIMc, nullptr, nullptr, nullptr);
  // ---- LN2 + fused router ----
  resln_router_kernel<<<NTOK, 256, 0, stream>>>(x1, aout, ln2_g, ln2_b, rw, rb, x2, x2h, topi, topwp, cnt);
  // ---- MoE (MT=128 for B-panel reuse; BK=32 pipelined double-buffer, 32KB LDS) ----
  scan_kernel<<<1, 64, 0, stream>>>(cnt, offs, pos);
  fill_kernel<<<NTOK / 256, 256, 0, stream>>>(topi, offs, pos, tlist, slotof);
  gemm_kernel<128, 32, false, true, 1><<<dim3(FFD / 128, NTOK / 128, NEXP), 256, 0, stream>>>(
      x2h, nullptr, w1t, nullptr, e_b1, hbuf, nullptr, NTOK, FFD, DIMc, tlist, cnt, offs);
  gemm_kernel<128, 32, false, false, 2><<<dim3(DIMc / 128, NTOK / 128, NEXP), 256, 0, stream>>>(
      hbuf, nullptr, w2t, nullptr, e_b2, eo, nullptr, NTOK, DIMc, FFD, nullptr, cnt, offs);
  final_kernel<<<NTOK, 256, 0, stream>>>(x2, eo, slotof, topwp, ln3_g, ln3_b, (float*)d_out);
}

// Round 16
// 1125.909 us; speedup vs baseline: 1.0709x; 1.0213x over previous
//
#include <hip/hip_runtime.h>

typedef unsigned short u16;
typedef unsigned int   u32;
typedef __bf16    bf16x8 __attribute__((ext_vector_type(8)));
typedef _Float16  f16x8  __attribute__((ext_vector_type(8)));
typedef _Float16  f16x4  __attribute__((ext_vector_type(4)));
typedef __fp16    fp16x2 __attribute__((ext_vector_type(2)));
typedef float     f32x4  __attribute__((ext_vector_type(4)));
typedef u16       u16x4  __attribute__((ext_vector_type(4)));

#define DEV static __device__ __forceinline__

#if __has_builtin(__builtin_amdgcn_mfma_f32_16x16x16f16)
#define HAVE_MFMA16 1
#else
#define HAVE_MFMA16 0
#endif

constexpr int DIMc  = 1024;
constexpr int NHEAD = 16;
constexpr int HDM   = 64;
constexpr int SLENc = 2048;
constexpr int NBAT  = 2;
constexpr int NTOK  = NBAT * SLENc;     // 4096
constexpr int FFD   = 4096;
constexpr int NEXP  = 8;
constexpr int NSLOT = 2 * NTOK;         // 8192
constexpr long TD   = (long)NTOK * DIMc;
constexpr float RSC = 2048.0f;          // residual scale 2^11
constexpr float RSCI = 1.0f / 2048.0f;
constexpr float LOG2E = 1.4426950408889634f;

// softmax exponential: native v_exp_f32 (computes 2^x) when available -> log2 domain;
// else fall back to natural domain with the fast __expf intrinsic (round-13 path).
#if __has_builtin(__builtin_amdgcn_exp2f)
#define SMDOM LOG2E
#define SMTHR 11.5415603f
DEV float expq(float x) { return __builtin_amdgcn_exp2f(x); }
#else
#define SMDOM 1.0f
#define SMTHR 8.0f
DEV float expq(float x) { return __expf(x); }
#endif

DEV u16 f2bf(float f) {
  u32 u = __float_as_uint(f);
  u += 0x7fffu + ((u >> 16) & 1u);
  return (u16)(u >> 16);
}
DEV float bf2f(u16 h) { return __uint_as_float(((u32)h) << 16); }
DEV float h2f(u16 u) { union { _Float16 h; u16 u_; } x; x.u_ = u; return (float)x.h; }

// f32 -> f16 high + scaled residual (v ~= h + r/2048, rel err ~2^-22)
DEV void split2v(float v, u16& h, u16& r) {
  _Float16 hh = (_Float16)v;
  float rf = (v - (float)hh) * RSC;
  union { _Float16 h_; u16 u_; } a, b;
  a.h_ = hh; b.h_ = (_Float16)rf;
  h = a.u_; r = b.u_;
}

DEV u32 pkrtz(float a, float b) {
  union { fp16x2 v; u32 u; } x;
  x.v = __builtin_amdgcn_cvt_pkrtz(a, b);
  return x.u;
}

DEV f16x4 mk4(u32 lo, u32 hi) {
  union { u32 u[2]; f16x4 v; } x;
  x.u[0] = lo; x.u[1] = hi;
  return x.v;
}

DEV void async16(const void* g, void* l) {
  __builtin_amdgcn_global_load_lds((const u32*)g, (u32*)l, 16, 0, 0);
}

DEV f32x4 mfma_bf(bf16x8 a, bf16x8 b, f32x4 c) {
  return __builtin_amdgcn_mfma_f32_16x16x32_bf16(a, b, c, 0, 0, 0);
}
DEV f32x4 mfma_h(f16x8 a, f16x8 b, f32x4 c) {
  return __builtin_amdgcn_mfma_f32_16x16x32_f16(a, b, c, 0, 0, 0);
}
#if HAVE_MFMA16
DEV f32x4 mfma16h(f16x4 a, f16x4 b, f32x4 c) {
  return __builtin_amdgcn_mfma_f32_16x16x16f16(a, b, c, 0, 0, 0);
}
#endif

// swizzled fragment read from a [64][64] u16 LDS tile (rows 128B, 16B blocks XOR'd by row&7)
DEV f16x8 ldfragh(const u16 (*T)[64], int row, int blk) {
  return *(const f16x8*)((const u16*)T + row * 64 + ((blk ^ (row & 7)) * 8));
}
// 8B V-fragment for 16x16x16 PV: elems k' = kc*4..+3 of k-block kn, row d
DEV f16x4 ldVfrag4(const u16 (*T)[64], int row, int kn, int kc) {
  const int blk = kn * 2 + (kc >> 1);
  const u16* p = (const u16*)T + row * 64 + ((blk ^ (row & 7)) * 8) + (kc & 1) * 4;
  return *(const f16x4*)p;
}

// fast GELU (tanh form): max abs err ~1e-3, below bf16 storage noise of h
DEV float gelu_fast(float v) {
  float arg = v * fmaf(0.044715f * v, v, 1.0f) * 0.7978845608028654f;
  return v / (1.0f + __expf(-2.0f * arg));
}

// ---------------- elementwise f32 -> 2-way f16 split ----------------
__global__ __launch_bounds__(256) void split2_kernel(
    const float* __restrict__ x, u16* __restrict__ o0, u16* __restrict__ o1, long n) {
  long i = ((long)blockIdx.x * 256 + threadIdx.x) * 4;
  if (i >= n) return;
  f32x4 v = *(const f32x4*)(x + i);
  u16x4 h, r;
#pragma unroll
  for (int j = 0; j < 4; ++j) { u16 a, b; split2v(v[j], a, b); h[j] = a; r[j] = b; }
  *(u16x4*)(o0 + i) = h;
  *(u16x4*)(o1 + i) = r;
}

// ---------------- weight transpose + f16 2-split (W[R][C] -> Wt[C][R]) ----------
__global__ __launch_bounds__(256) void wsplit2_kernel(
    const float* __restrict__ W, u16* __restrict__ t0, u16* __restrict__ t1, int R, int C) {
  __shared__ alignas(16) float tile[32][33];
  const long base = (long)blockIdx.z * R * C;
  const int c0 = blockIdx.x * 32, r0 = blockIdx.y * 32;
  const int tx = threadIdx.x & 31, ty = threadIdx.x >> 5;
#pragma unroll
  for (int i = 0; i < 32; i += 8)
    tile[ty + i][tx] = W[base + (long)(r0 + ty + i) * C + (c0 + tx)];
  __syncthreads();
#pragma unroll
  for (int i = 0; i < 32; i += 8) {
    float v = tile[tx][ty + i];
    long oidx = base + (long)(c0 + ty + i) * R + (r0 + tx);
    u16 a, b; split2v(v, a, b);
    t0[oidx] = a; t1[oidx] = b;
  }
}

// ---------------- weight transpose -> single bf16 plane (MoE experts) ----------
__global__ __launch_bounds__(256) void wsplit1_kernel(
    const float* __restrict__ W, u16* __restrict__ t0, int R, int C) {
  __shared__ alignas(16) float tile[32][33];
  const long base = (long)blockIdx.z * R * C;
  const int c0 = blockIdx.x * 32, r0 = blockIdx.y * 32;
  const int tx = threadIdx.x & 31, ty = threadIdx.x >> 5;
#pragma unroll
  for (int i = 0; i < 32; i += 8)
    tile[ty + i][tx] = W[base + (long)(r0 + ty + i) * C + (c0 + tx)];
  __syncthreads();
#pragma unroll
  for (int i = 0; i < 32; i += 8) {
    long oidx = base + (long)(c0 + ty + i) * R + (r0 + tx);
    t0[oidx] = f2bf(tile[tx][ty + i]);
  }
}

// ---------------- bias concat: [bq|bk|bv] and [bk_c|bv_c] ----------------
__global__ __launch_bounds__(256) void biascat_kernel(
    const float* __restrict__ q, const float* __restrict__ k, const float* __restrict__ v,
    const float* __restrict__ ck, const float* __restrict__ cv,
    float* __restrict__ qkvb, float* __restrict__ kvb) {
  int i = blockIdx.x * 256 + threadIdx.x;
  if (i < 1024) qkvb[i] = q[i];
  else if (i < 2048) qkvb[i] = k[i - 1024];
  else if (i < 3072) qkvb[i] = v[i - 2048];
  else if (i < 4096) kvb[i - 3072] = ck[i - 3072];
  else if (i < 5120) kvb[i - 3072] = cv[i - 4096];
}

// ---------------- V transpose from split planes: V[t][ld] -> Vt[bh][d][s] ------
__global__ __launch_bounds__(256) void vtrans2_kernel(
    const u16* __restrict__ vh, const u16* __restrict__ vr, int ld,
    u16* __restrict__ t0, u16* __restrict__ t1) {
  __shared__ alignas(16) float tile[32][33];
  const int bh = blockIdx.z, b = bh >> 4, h = bh & 15;
  const int s0 = blockIdx.x * 32, d0 = blockIdx.y * 32;
  const int tx = threadIdx.x & 31, ty = threadIdx.x >> 5;
#pragma unroll
  for (int i = 0; i < 32; i += 8) {
    long idx = (long)(b * SLENc + s0 + ty + i) * ld + h * HDM + d0 + tx;
    tile[ty + i][tx] = h2f(vh[idx]) + h2f(vr[idx]) * RSCI;
  }
  __syncthreads();
#pragma unroll
  for (int i = 0; i < 32; i += 8) {
    float v = tile[tx][ty + i];
    long o = ((long)bh * HDM + d0 + ty + i) * SLENc + s0 + tx;
    u16 a, b_; split2v(v, a, b_);
    t0[o] = a; t1[o] = b_;
  }
}

// ---------------- GEMM: C[M][N] = A[M][K] @ Bt[N][K]^T (+bias, epilogue) --------
// MT: M-tile (64 or 128). N-tile fixed 128. SPLIT: f16 2-way split (3 mfma terms).
// BK=32: linear LDS, double-buffered prefetch pipeline (T3-min).
// EPI 0: f32 out; 1: gelu->bf16; 2: ->bf16; 3: f16 2-split planes (Cout,C1)
template<int MT, int BK, bool SPLIT, bool GATHER, int EPI>
__global__ __launch_bounds__(256) void gemm_kernel(
    const u16* __restrict__ A0, const u16* __restrict__ A1,
    const u16* __restrict__ B0, const u16* __restrict__ B1,
    const float* __restrict__ bias, void* __restrict__ Cout, u16* __restrict__ C1,
    int M, int N, int Kd,
    const int* __restrict__ tlist, const int* __restrict__ cnts, const int* __restrict__ offs) {
  constexpr int NP   = SPLIT ? 2 : 1;
  constexpr int NBUF = (BK == 32) ? 2 : 1;  // pipeline only BK=32
  constexpr int RPC  = 512 / BK;            // rows per 1KB staging chunk
  constexpr int ACH  = (MT / RPC) / 4;      // a-chunks per wave
  constexpr int BCH  = (128 / RPC) / 4;     // b-chunks per wave
  constexpr int MREP = MT / 32;             // m-fragments per wave
  constexpr int WRS  = MT / 2;              // per-wave row span
  __shared__ alignas(16) u16 As[NBUF][NP][MT * BK];
  __shared__ alignas(16) u16 Bs[NBUF][NP][128 * BK];

  const int e   = blockIdx.z;
  const int cnt = cnts ? cnts[e] : M;
  const int off = offs ? offs[e] : 0;
  const int m0  = blockIdx.y * MT;
  if (m0 >= cnt) return;
  const int n0  = blockIdx.x * 128;

  const int tid = threadIdx.x;
  const int lane = tid & 63, wid = tid >> 6;
  const int fr = lane & 15, kc = lane >> 4;
  const int wr = wid >> 1, wc = wid & 1;

  const long boff = (long)e * N * Kd;

  int srow, kseg8;
  if constexpr (BK == 32) { srow = lane >> 2; kseg8 = lane & 3; }
  else                    { srow = lane >> 3; kseg8 = (lane & 7) ^ (srow & 7); }

  long aoff[ACH], boff_[BCH];
#pragma unroll
  for (int c = 0; c < ACH; ++c) {
    const int row = (wid * ACH + c) * RPC + srow;
    long ar;
    if (GATHER) {
      int idx = m0 + row; if (idx >= cnt) idx = cnt - 1;
      ar = tlist[off + idx];
    } else {
      ar = (long)(off + m0 + row);
    }
    aoff[c] = ar * Kd + kseg8 * 8;
  }
#pragma unroll
  for (int c = 0; c < BCH; ++c) {
    const int row = (wid * BCH + c) * RPC + srow;
    boff_[c] = boff + (long)(n0 + row) * Kd + kseg8 * 8;
  }

  f32x4 acc[MREP][4], acc1[MREP][4];
#pragma unroll
  for (int m = 0; m < MREP; ++m)
#pragma unroll
    for (int n = 0; n < 4; ++n) { acc[m][n] = f32x4{0.f,0.f,0.f,0.f}; acc1[m][n] = f32x4{0.f,0.f,0.f,0.f}; }

  auto stage = [&](int kt, int bufi) {
    const int k0 = kt * BK;
#pragma unroll
    for (int c = 0; c < ACH; ++c) {
      const int chunk = wid * ACH + c;
      async16(A0 + aoff[c] + k0, &As[bufi][0][chunk * 512]);
      if constexpr (SPLIT) async16(A1 + aoff[c] + k0, &As[bufi][1][chunk * 512]);
    }
#pragma unroll
    for (int c = 0; c < BCH; ++c) {
      const int chunk = wid * BCH + c;
      async16(B0 + boff_[c] + k0, &Bs[bufi][0][chunk * 512]);
      if constexpr (SPLIT) async16(B1 + boff_[c] + k0, &Bs[bufi][1][chunk * 512]);
    }
  };

  auto compute = [&](int bufi) {
    if constexpr (BK == 32) {
      if constexpr (SPLIT) {
        f16x8 a0[MREP], a1[MREP];
#pragma unroll
        for (int m = 0; m < MREP; ++m) {
          const int idx = (wr * WRS + m * 16 + fr) * 32 + kc * 8;
          a0[m] = *(const f16x8*)&As[bufi][0][idx];
          a1[m] = *(const f16x8*)&As[bufi][1][idx];
        }
#pragma unroll
        for (int n = 0; n < 4; ++n) {
          const int idx = (wc * 64 + n * 16 + fr) * 32 + kc * 8;
          f16x8 b0 = *(const f16x8*)&Bs[bufi][0][idx];
          f16x8 b1 = *(const f16x8*)&Bs[bufi][1][idx];
#pragma unroll
          for (int m = 0; m < MREP; ++m) {
            acc[m][n]  = mfma_h(a0[m], b0, acc[m][n]);
            acc1[m][n] = mfma_h(a0[m], b1, acc1[m][n]);
            acc1[m][n] = mfma_h(a1[m], b0, acc1[m][n]);
          }
        }
      } else {
        bf16x8 a0[MREP];
#pragma unroll
        for (int m = 0; m < MREP; ++m)
          a0[m] = *(const bf16x8*)&As[bufi][0][(wr * WRS + m * 16 + fr) * 32 + kc * 8];
#pragma unroll
        for (int n = 0; n < 4; ++n) {
          bf16x8 b0 = *(const bf16x8*)&Bs[bufi][0][(wc * 64 + n * 16 + fr) * 32 + kc * 8];
#pragma unroll
          for (int m = 0; m < MREP; ++m)
            acc[m][n] = mfma_bf(a0[m], b0, acc[m][n]);
        }
      }
    } else {
      // BK=64, bf16 only. XOR-swizzled reads: blk' = blk ^ (row&7); row&7 == fr&7.
#pragma unroll
      for (int ksub = 0; ksub < 2; ++ksub) {
        bf16x8 a0[MREP];
#pragma unroll
        for (int m = 0; m < MREP; ++m) {
          const int row = wr * WRS + m * 16 + fr;
          a0[m] = *(const bf16x8*)&As[0][0][row * 64 + (((ksub << 2) | kc) ^ (fr & 7)) * 8];
        }
#pragma unroll
        for (int n = 0; n < 4; ++n) {
          const int row = wc * 64 + n * 16 + fr;
          bf16x8 b0 = *(const bf16x8*)&Bs[0][0][row * 64 + (((ksub << 2) | kc) ^ (fr & 7)) * 8];
#pragma unroll
          for (int m = 0; m < MREP; ++m)
            acc[m][n] = mfma_bf(a0[m], b0, acc[m][n]);
        }
      }
    }
  };

  const int NK = Kd / BK;
  if constexpr (BK == 32) {
    // T3-min pipelined double buffer: prefetch kt+1 before computing kt.
    stage(0, 0);
    int cur = 0;
    for (int kt = 0; kt < NK; ++kt) {
      __syncthreads();                       // drains vmcnt -> tile kt ready; all waves done with other buf
      if (kt + 1 < NK) stage(kt + 1, cur ^ 1);
      compute(cur);
      cur ^= 1;
    }
  } else {
    for (int kt = 0; kt < NK; ++kt) {
      __syncthreads();
      stage(kt, 0);
      __syncthreads();
      compute(0);
    }
  }

  const float* bvec = bias + (long)e * N;
#pragma unroll
  for (int m = 0; m < MREP; ++m) {
#pragma unroll
    for (int j = 0; j < 4; ++j) {
      const int r = m0 + wr * WRS + m * 16 + kc * 4 + j;
      if (r >= cnt) continue;
      const long orow = (long)(off + r) * N;
#pragma unroll
      for (int n = 0; n < 4; ++n) {
        const int col = n0 + wc * 64 + n * 16 + fr;
        float v = acc[m][n][j];
        if constexpr (SPLIT) v += acc1[m][n][j] * RSCI;
        v += bvec[col];
        if constexpr (EPI == 0) {
          ((float*)Cout)[orow + col] = v;
        } else if constexpr (EPI == 1) {
          ((u16*)Cout)[orow + col] = f2bf(gelu_fast(v));
        } else if constexpr (EPI == 2) {
          ((u16*)Cout)[orow + col] = f2bf(v);
        } else {
          u16 a_, b_; split2v(v, a_, b_);
          ((u16*)Cout)[orow + col] = a_;
          C1[orow + col] = b_;
        }
      }
    }
  }
}

// ---------------- MFMA flash attention, f16 2-split, QBLK=128 / 8 waves --------
#if !HAVE_MFMA16
DEV f16x8 gather_fragh(u32 a0, u32 a1, u32 b0, u32 b1, int lane) {
  const int kc = lane >> 4;
  const int base = (lane & 15) + ((kc & 1) << 5);
  union { u32 u[4]; f16x8 v; } r;
  u32 s00 = (u32)__shfl((int)a0, base, 64);
  u32 s01 = (u32)__shfl((int)a1, base, 64);
  u32 s10 = (u32)__shfl((int)b0, base, 64);
  u32 s11 = (u32)__shfl((int)b1, base, 64);
  u32 t00 = (u32)__shfl((int)a0, base + 16, 64);
  u32 t01 = (u32)__shfl((int)a1, base + 16, 64);
  u32 t10 = (u32)__shfl((int)b0, base + 16, 64);
  u32 t11 = (u32)__shfl((int)b1, base + 16, 64);
  const bool hi = (kc >> 1) != 0;
  r.u[0] = hi ? s10 : s00;
  r.u[1] = hi ? s11 : s01;
  r.u[2] = hi ? t10 : t00;
  r.u[3] = hi ? t11 : t01;
  return r.v;
}
#endif

template<bool CAUSAL>
__global__ __launch_bounds__(512, 4) void attn2_kernel(
    const u16* __restrict__ Qh, const u16* __restrict__ Qr, int qld,
    const u16* __restrict__ Kh, const u16* __restrict__ Kr, int kld,
    const u16* __restrict__ Vh, const u16* __restrict__ Vr,
    u16* __restrict__ OH, u16* __restrict__ OR) {
  __shared__ alignas(16) u16 KQs[2][2][64][64];   // [buf][plane][row][col]
  __shared__ alignas(16) u16 Vts[2][2][64][64];

  // LPT schedule for causal: heavy blocks (large qt => most k-tiles) launch first
  const int qt = CAUSAL ? ((int)gridDim.x - 1 - (int)blockIdx.x) : (int)blockIdx.x;
  const int h = blockIdx.y, b = blockIdx.z;
  const int tid = threadIdx.x, lane = tid & 63, w = tid >> 6;   // w in 0..7
  const int wq = w >> 2, wl = w & 3;          // q-half, role within half
  const int fr = lane & 15, kc = lane >> 4;
  const int q0 = qt * 128;
  const int qrow = wq * 64 + wl * 16 + fr;    // q row within block (0..127)
  const int qglob = q0 + qrow;                // global q row (causal mask RHS)
  const long qbase = (long)(b * SLENc) * qld + h * HDM;
  const long kbase = (long)(b * SLENc) * kld + h * HDM;
  const long obase = (long)(b * SLENc) * DIMc + h * HDM;
  const long vtbase = (long)(b * NHEAD + h) * HDM * SLENc;
  const int r = lane >> 3, blk = (lane & 7) ^ r;

  auto stageKV = [&](int kt, int bufi) {
    // 8 waves: wave w loads rows 8w..8w+7 of the 64-row K and V tiles
#pragma unroll
    for (int p = 0; p < 2; ++p) {
      const u16* gp = (p == 0 ? Kh : Kr);
      async16(gp + kbase + (long)(kt * 64 + 8 * w + r) * kld + blk * 8, &KQs[bufi][p][8 * w][0]);
    }
    const long vrow = vtbase + kt * 64;
#pragma unroll
    for (int p = 0; p < 2; ++p) {
      const u16* gp = (p == 0 ? Vh : Vr);
      async16(gp + vrow + (long)(8 * w + r) * SLENc + blk * 8, &Vts[bufi][p][8 * w][0]);
    }
  };

  // ---- prologue: stage 128 Q rows (half0 -> KQs[0], half1 -> Vts[0]) ----
#pragma unroll
  for (int hh = 0; hh < 2; ++hh) {
#pragma unroll
    for (int p = 0; p < 2; ++p) {
      const u16* gp = (p == 0 ? Qh : Qr);
      u16* dst = hh == 0 ? &KQs[0][p][8 * w][0] : &Vts[0][p][8 * w][0];
      async16(gp + qbase + (long)(q0 + hh * 64 + 8 * w + r) * qld + blk * 8, dst);
    }
  }
  __syncthreads();
  f16x8 qf0[2], qf1[2];
  {
    const u16 (*Q0)[64] = (wq == 0) ? KQs[0][0] : Vts[0][0];
    const u16 (*Q1)[64] = (wq == 0) ? KQs[0][1] : Vts[0][1];
#pragma unroll
    for (int s = 0; s < 2; ++s) {
      qf0[s] = ldfragh(Q0, wl * 16 + fr, s * 4 + kc);
      qf1[s] = ldfragh(Q1, wl * 16 + fr, s * 4 + kc);
    }
  }
  // prefetch K/V tile 0 into buf1 (doesn't touch buf0 just read)
  stageKV(0, 1);

  f32x4 accO0[4], accO1[4];
#pragma unroll
  for (int dn = 0; dn < 4; ++dn) { accO0[dn] = f32x4{0.f,0.f,0.f,0.f}; accO1[dn] = f32x4{0.f,0.f,0.f,0.f}; }
  float m_ = -3e38f, l_ = 0.f;   // m_ in expq domain

  const int nkt = CAUSAL ? (2 * qt + 2) : (SLENc / 64);
  int cur = 1;
  for (int kt = 0; kt < nkt; ++kt) {
    __syncthreads();                        // tile kt landed in bufs[cur]; all waves done with bufs[cur^1]
    if (kt + 1 < nkt) stageKV(kt + 1, cur ^ 1);

    // ---- QK^T (swapped): sc at (k = kn*16 + kc*4 + j, q = fr) ----
    f32x4 sc0[4], sc1[4];
#pragma unroll
    for (int kn = 0; kn < 4; ++kn) { sc0[kn] = f32x4{0.f,0.f,0.f,0.f}; sc1[kn] = f32x4{0.f,0.f,0.f,0.f}; }
    __builtin_amdgcn_s_setprio(1);
#pragma unroll
    for (int kn = 0; kn < 4; ++kn)
#pragma unroll
      for (int s = 0; s < 2; ++s) {
        f16x8 ah = ldfragh(KQs[cur][0], kn * 16 + fr, s * 4 + kc);
        f16x8 ar = ldfragh(KQs[cur][1], kn * 16 + fr, s * 4 + kc);
        sc0[kn] = mfma_h(ah, qf0[s], sc0[kn]);
        sc1[kn] = mfma_h(ah, qf1[s], sc1[kn]);
        sc1[kn] = mfma_h(ar, qf0[s], sc1[kn]);
      }
    __builtin_amdgcn_s_setprio(0);

    // ---- online softmax (per-lane row q = fr; domain set by expq) ----
    constexpr float SCL = 0.125f * SMDOM, SCL2 = 0.125f * RSCI * SMDOM;
    float p_[4][4];
    float mx = -3e38f;
#pragma unroll
    for (int kn = 0; kn < 4; ++kn)
#pragma unroll
      for (int j = 0; j < 4; ++j) {
        float sv = fmaf(sc0[kn][j], SCL, sc1[kn][j] * SCL2);
        if (CAUSAL) {
          if (kt * 64 + kn * 16 + kc * 4 + j > qglob) sv = -3e38f;  // absolute key idx vs global q idx
        }
        p_[kn][j] = sv;
        mx = fmaxf(mx, sv);
      }
    mx = fmaxf(mx, __shfl_xor(mx, 16, 64));
    mx = fmaxf(mx, __shfl_xor(mx, 32, 64));
    // T13 defer-rescale: skip when max growth fits e^8 headroom (domain-scaled)
    if (!__all(mx <= m_ + SMTHR)) {
      const float mn = fmaxf(m_, mx);
      const float corr = expq(m_ - mn);
      m_ = mn;
      l_ *= corr;
#pragma unroll
      for (int dn = 0; dn < 4; ++dn) { accO0[dn] *= corr; accO1[dn] *= corr; }
    }
    float rs = 0.f;
#pragma unroll
    for (int kn = 0; kn < 4; ++kn)
#pragma unroll
      for (int j = 0; j < 4; ++j) {
        float p = expq(p_[kn][j] - m_);
        p_[kn][j] = p;
        rs += p;
      }
    rs += __shfl_xor(rs, 16, 64);
    rs += __shfl_xor(rs, 32, 64);
    l_ += rs;

#if HAVE_MFMA16
    // ---- PV via 16x16x16 mfma: B-frag (P column q=fr, k=kc*4+j) is lane-local ----
#pragma unroll
    for (int kn = 0; kn < 4; ++kn) {
      u32 hp0 = pkrtz(p_[kn][0], p_[kn][1]);
      u32 hp1 = pkrtz(p_[kn][2], p_[kn][3]);
      float h0 = h2f((u16)hp0), h1 = h2f((u16)(hp0 >> 16));
      float h2_ = h2f((u16)hp1), h3 = h2f((u16)(hp1 >> 16));
      u32 rp0 = pkrtz((p_[kn][0] - h0) * RSC, (p_[kn][1] - h1) * RSC);
      u32 rp1 = pkrtz((p_[kn][2] - h2_) * RSC, (p_[kn][3] - h3) * RSC);
      f16x4 ph = mk4(hp0, hp1), pr = mk4(rp0, rp1);
      __builtin_amdgcn_s_setprio(1);
#pragma unroll
      for (int dn = 0; dn < 4; ++dn) {
        f16x4 vh = ldVfrag4(Vts[cur][0], dn * 16 + fr, kn, kc);
        f16x4 vr = ldVfrag4(Vts[cur][1], dn * 16 + fr, kn, kc);
        accO0[dn] = mfma16h(vh, ph, accO0[dn]);
        accO1[dn] = mfma16h(vh, pr, accO1[dn]);
        accO1[dn] = mfma16h(vr, ph, accO1[dn]);
      }
      __builtin_amdgcn_s_setprio(0);
    }
#else
    // ---- fallback: split P, redistribute via lane gathers, 16x16x32 PV ----
    u32 hpk[4][2], rpk[4][2];
#pragma unroll
    for (int kn = 0; kn < 4; ++kn)
#pragma unroll
      for (int jp = 0; jp < 2; ++jp) {
        float p0 = p_[kn][2 * jp], p1 = p_[kn][2 * jp + 1];
        u32 hp = pkrtz(p0, p1);
        float h0 = h2f((u16)hp), h1 = h2f((u16)(hp >> 16));
        u32 rp = pkrtz((p0 - h0) * RSC, (p1 - h1) * RSC);
        hpk[kn][jp] = hp;
        rpk[kn][jp] = rp;
      }
#pragma unroll
    for (int s = 0; s < 2; ++s) {
      f16x8 ph = gather_fragh(hpk[2 * s][0], hpk[2 * s][1], hpk[2 * s + 1][0], hpk[2 * s + 1][1], lane);
      f16x8 pr = gather_fragh(rpk[2 * s][0], rpk[2 * s][1], rpk[2 * s + 1][0], rpk[2 * s + 1][1], lane);
      __builtin_amdgcn_s_setprio(1);
#pragma unroll
      for (int dn = 0; dn < 4; ++dn) {
        f16x8 vh = ldfragh(Vts[cur][0], dn * 16 + fr, s * 4 + kc);
        f16x8 vr = ldfragh(Vts[cur][1], dn * 16 + fr, s * 4 + kc);
        accO0[dn] = mfma_h(vh, ph, accO0[dn]);
        accO1[dn] = mfma_h(vh, pr, accO1[dn]);
        accO1[dn] = mfma_h(vr, ph, accO1[dn]);
      }
      __builtin_amdgcn_s_setprio(0);
    }
#endif
    cur ^= 1;
  }

  const float inv = 1.0f / l_;
#pragma unroll
  for (int dn = 0; dn < 4; ++dn) {
    u16x4 hv, rv;
#pragma unroll
    for (int j = 0; j < 4; ++j) {
      float o = (accO0[dn][j] + accO1[dn][j] * RSCI) * inv;
      u16 a_, b_; split2v(o, a_, b_);
      hv[j] = a_; rv[j] = b_;
    }
    const long oidx = obase + (long)(q0 + qrow) * DIMc + dn * 16 + kc * 4;
    *(u16x4*)&OH[oidx] = hv;
    *(u16x4*)&OR[oidx] = rv;
  }
}

// ---------------- residual + layernorm (+ optional split outputs) ----------------
template<int NS>
__global__ __launch_bounds__(256) void resln_kernel(
    const float* __restrict__ resid, const float* __restrict__ proj,
    const float* __restrict__ gam, const float* __restrict__ bet,
    float* __restrict__ yout, u16* __restrict__ s0, u16* __restrict__ s1) {
  __shared__ float red[4];
  const int t = blockIdx.x, tid = threadIdx.x;
  const long base = (long)t * DIMc;
  float v[4];
#pragma unroll
  for (int i = 0; i < 4; ++i) {
    int d = tid + i * 256;
    v[i] = resid[base + d] + proj[base + d];
  }
  float s = v[0] + v[1] + v[2] + v[3];
#pragma unroll
  for (int o = 32; o; o >>= 1) s += __shfl_xor(s, o, 64);
  if ((tid & 63) == 0) red[tid >> 6] = s;
  __syncthreads();
  const float mean = (red[0] + red[1] + red[2] + red[3]) * (1.0f / DIMc);
  __syncthreads();
  float q = 0.f;
#pragma unroll
  for (int i = 0; i < 4; ++i) { float d_ = v[i] - mean; q += d_ * d_; }
#pragma unroll
  for (int o = 32; o; o >>= 1) q += __shfl_xor(q, o, 64);
  if ((tid & 63) == 0) red[tid >> 6] = q;
  __syncthreads();
  const float var = (red[0] + red[1] + red[2] + red[3]) * (1.0f / DIMc);
  const float inv = rsqrtf(var + 1e-5f);
#pragma unroll
  for (int i = 0; i < 4; ++i) {
    int d = tid + i * 256;
    float y = (v[i] - mean) * inv * gam[d] + bet[d];
    yout[base + d] = y;
    if constexpr (NS == 1) s0[base + d] = f2bf(y);
    if constexpr (NS == 2) {
      u16 a, b; split2v(y, a, b);
      s0[base + d] = a; s1[base + d] = b;
    }
  }
}

// ---------------- residual + LN2 + fused router (logits, top-2, counts) --------
__global__ __launch_bounds__(256) void resln_router_kernel(
    const float* __restrict__ resid, const float* __restrict__ proj,
    const float* __restrict__ gam, const float* __restrict__ bet,
    const float* __restrict__ rw, const float* __restrict__ rb,
    float* __restrict__ yout, u16* __restrict__ s0,
    int* __restrict__ topi, float* __restrict__ topw, int* __restrict__ cnt) {
  __shared__ float red[4];
  __shared__ float rpart[4][8];
  const int t = blockIdx.x, tid = threadIdx.x;
  const int lane = tid & 63, wv = tid >> 6;
  const long base = (long)t * DIMc;
  float v[4];
#pragma unroll
  for (int i = 0; i < 4; ++i) {
    int d = tid + i * 256;
    v[i] = resid[base + d] + proj[base + d];
  }
  float s = v[0] + v[1] + v[2] + v[3];
#pragma unroll
  for (int o = 32; o; o >>= 1) s += __shfl_xor(s, o, 64);
  if (lane == 0) red[wv] = s;
  __syncthreads();
  const float mean = (red[0] + red[1] + red[2] + red[3]) * (1.0f / DIMc);
  __syncthreads();
  float q = 0.f;
#pragma unroll
  for (int i = 0; i < 4; ++i) { float d_ = v[i] - mean; q += d_ * d_; }
#pragma unroll
  for (int o = 32; o; o >>= 1) q += __shfl_xor(q, o, 64);
  if (lane == 0) red[wv] = q;
  __syncthreads();
  const float var = (red[0] + red[1] + red[2] + red[3]) * (1.0f / DIMc);
  const float inv = rsqrtf(var + 1e-5f);
  float part[8] = {};
#pragma unroll
  for (int i = 0; i < 4; ++i) {
    int d = tid + i * 256;
    float y = (v[i] - mean) * inv * gam[d] + bet[d];
    yout[base + d] = y;
    s0[base + d] = f2bf(y);
    const f32x4* wp = (const f32x4*)&rw[d * 8];
    f32x4 w0 = wp[0], w1 = wp[1];
    part[0] += y * w0[0]; part[1] += y * w0[1]; part[2] += y * w0[2]; part[3] += y * w0[3];
    part[4] += y * w1[0]; part[5] += y * w1[1]; part[6] += y * w1[2]; part[7] += y * w1[3];
  }
#pragma unroll
  for (int o = 32; o; o >>= 1)
#pragma unroll
    for (int e = 0; e < 8; ++e) part[e] += __shfl_xor(part[e], o, 64);
  if (lane == 0)
#pragma unroll
    for (int e = 0; e < 8; ++e) rpart[wv][e] = part[e];
  __syncthreads();
  if (tid == 0) {
    float lg[8];
#pragma unroll
    for (int e = 0; e < 8; ++e)
      lg[e] = rpart[0][e] + rpart[1][e] + rpart[2][e] + rpart[3][e] + rb[e];
    int i1 = 0;
#pragma unroll
    for (int e = 1; e < 8; ++e) if (lg[e] > lg[i1]) i1 = e;
    int i2 = (i1 == 0) ? 1 : 0;
#pragma unroll
    for (int e = 0; e < 8; ++e) if (e != i1 && lg[e] > lg[i2]) i2 = e;
    float mx = lg[i1], ps = 0.f, p[8];
#pragma unroll
    for (int e = 0; e < 8; ++e) { p[e] = __expf(lg[e] - mx); ps += p[e]; }
    float p1 = p[i1] / ps, p2 = p[i2] / ps;
    float e2 = __expf(p2 - p1);
    float w1 = 1.0f / (1.0f + e2);
    topi[t * 2] = i1; topi[t * 2 + 1] = i2;
    topw[t * 2] = w1; topw[t * 2 + 1] = e2 * w1;
    atomicAdd(&cnt[i1], 1); atomicAdd(&cnt[i2], 1);
  }
}

__global__ void scan_kernel(const int* __restrict__ cnt, int* __restrict__ offs, int* __restrict__ pos) {
  if (threadIdx.x == 0) {
    int a = 0;
    for (int e = 0; e < NEXP; ++e) { offs[e] = a; a += cnt[e]; }
  }
  if (threadIdx.x < NEXP) pos[threadIdx.x] = 0;
}

__global__ __launch_bounds__(256) void fill_kernel(
    const int* __restrict__ topi, const int* __restrict__ offs, int* __restrict__ pos,
    int* __restrict__ tlist, int* __restrict__ slotof) {
  int t = blockIdx.x * 256 + threadIdx.x;
  if (t >= NTOK) return;
#pragma unroll
  for (int k = 0; k < 2; ++k) {
    int e = topi[t * 2 + k];
    int pp = atomicAdd(&pos[e], 1);
    int s = offs[e] + pp;
    tlist[s] = t;
    slotof[t * 2 + k] = s;
  }
}

// ---------------- final: combine experts + residual + LN3 -> f32 out ----------------
__global__ __launch_bounds__(256) void final_kernel(
    const float* __restrict__ x2, const u16* __restrict__ eo,
    const int* __restrict__ slotof, const float* __restrict__ topw,
    const float* __restrict__ gam, const float* __restrict__ bet, float* __restrict__ out) {
  __shared__ float red[4];
  const int t = blockIdx.x, tid = threadIdx.x;
  const long base = (long)t * DIMc;
  const int s0 = slotof[t * 2], s1 = slotof[t * 2 + 1];
  const float w0 = topw[t * 2], w1 = topw[t * 2 + 1];
  float v[4];
#pragma unroll
  for (int i = 0; i < 4; ++i) {
    int d = tid + i * 256;
    float moe = w0 * bf2f(eo[(long)s0 * DIMc + d]) + w1 * bf2f(eo[(long)s1 * DIMc + d]);
    v[i] = x2[base + d] + moe;
  }
  float s = v[0] + v[1] + v[2] + v[3];
#pragma unroll
  for (int o = 32; o; o >>= 1) s += __shfl_xor(s, o, 64);
  if ((tid & 63) == 0) red[tid >> 6] = s;
  __syncthreads();
  const float mean = (red[0] + red[1] + red[2] + red[3]) * (1.0f / DIMc);
  __syncthreads();
  float q = 0.f;
#pragma unroll
  for (int i = 0; i < 4; ++i) { float d_ = v[i] - mean; q += d_ * d_; }
#pragma unroll
  for (int o = 32; o; o >>= 1) q += __shfl_xor(q, o, 64);
  if ((tid & 63) == 0) red[tid >> 6] = q;
  __syncthreads();
  const float var = (red[0] + red[1] + red[2] + red[3]) * (1.0f / DIMc);
  const float inv = rsqrtf(var + 1e-5f);
#pragma unroll
  for (int i = 0; i < 4; ++i) {
    int d = tid + i * 256;
    out[base + d] = (v[i] - mean) * inv * gam[d] + bet[d];
  }
}

// ---------------- host orchestration ----------------
extern "C" void kernel_launch(void* const* d_in, const int* in_sizes, int n_in,
                              void* d_out, int out_size, void* d_ws, size_t ws_size,
                              hipStream_t stream) {
  (void)in_sizes; (void)n_in; (void)out_size; (void)ws_size;
  const float* x     = (const float*)d_in[0];
  const float* enc   = (const float*)d_in[1];
  const float* aw[8] = {(const float*)d_in[2],  (const float*)d_in[4],  (const float*)d_in[6],  (const float*)d_in[8],
                        (const float*)d_in[10], (const float*)d_in[12], (const float*)d_in[14], (const float*)d_in[16]};
  const float* ab[8] = {(const float*)d_in[3],  (const float*)d_in[5],  (const float*)d_in[7],  (const float*)d_in[9],
                        (const float*)d_in[11], (const float*)d_in[13], (const float*)d_in[15], (const float*)d_in[17]};
  const float* ln1_g = (const float*)d_in[18]; const float* ln1_b = (const float*)d_in[19];
  const float* ln2_g = (const float*)d_in[20]; const float* ln2_b = (const float*)d_in[21];
  const float* ln3_g = (const float*)d_in[22]; const float* ln3_b = (const float*)d_in[23];
  const float* rw    = (const float*)d_in[24]; const float* rb    = (const float*)d_in[25];
  const float* e_w1  = (const float*)d_in[26]; const float* e_b1  = (const float*)d_in[27];
  const float* e_w2  = (const float*)d_in[28]; const float* e_b2  = (const float*)d_in[29];

  char* basep = (char*)d_ws;
  size_t offb = 0;
  auto alloc = [&](size_t nbytes) -> void* {
    void* r = basep + offb;
    offb += (nbytes + 255) & ~(size_t)255;
    return r;
  };

  const size_t PLANE_BF = (size_t)TD * 2;   // 8 MB u16 plane
  const size_t PLANE_F  = (size_t)TD * 4;   // 16 MB f32 plane
  const size_t WPLANE   = (size_t)DIMc * DIMc * 2;  // 2 MB weight plane

  u16 *xs0 = (u16*)alloc(PLANE_BF), *xs1 = (u16*)alloc(PLANE_BF);
  u16 *es0 = (u16*)alloc(PLANE_BF), *es1 = (u16*)alloc(PLANE_BF);
  u16 *os0 = (u16*)alloc(PLANE_BF), *os1 = (u16*)alloc(PLANE_BF);
  u16 *wqkv0 = (u16*)alloc(3 * WPLANE), *wqkv1 = (u16*)alloc(3 * WPLANE);
  u16 *wkv0  = (u16*)alloc(2 * WPLANE), *wkv1  = (u16*)alloc(2 * WPLANE);
  u16 *wq0   = (u16*)alloc(WPLANE),     *wq1   = (u16*)alloc(WPLANE);
  u16 *wo10  = (u16*)alloc(WPLANE),     *wo11  = (u16*)alloc(WPLANE);
  u16 *wo20  = (u16*)alloc(WPLANE),     *wo21  = (u16*)alloc(WPLANE);
  u16* w1t = (u16*)alloc((size_t)NEXP * FFD * DIMc * 2);
  u16* w2t = (u16*)alloc((size_t)NEXP * DIMc * FFD * 2);
  u16 *QKVh = (u16*)alloc(3 * PLANE_BF), *QKVr = (u16*)alloc(3 * PLANE_BF);
  u16 *KVh  = (u16*)alloc(2 * PLANE_BF), *KVr  = (u16*)alloc(2 * PLANE_BF);
  u16 *Qch  = (u16*)alloc(PLANE_BF),     *Qcr  = (u16*)alloc(PLANE_BF);
  u16 *Vth  = (u16*)alloc(PLANE_BF),     *Vtr  = (u16*)alloc(PLANE_BF);
  float* qkvb = (float*)alloc(3072 * 4);
  float* kvb  = (float*)alloc(2048 * 4);
  float* aout = (float*)alloc(PLANE_F);
  float* x1   = (float*)alloc(PLANE_F);
  float* x2   = (float*)alloc(PLANE_F);
  u16*   x2h  = (u16*)alloc(PLANE_BF);
  u16*   hbuf = (u16*)alloc((size_t)(NSLOT + 128) * FFD * 2);
  u16*   eo   = (u16*)alloc((size_t)NSLOT * DIMc * 2);
  int*   topi   = (int*)alloc(NSLOT * 4);
  float* topwp  = (float*)alloc(NSLOT * 4);
  int*   tlist  = (int*)alloc(NSLOT * 4);
  int*   slotof = (int*)alloc(NSLOT * 4);
  int*   cnt    = (int*)alloc(NEXP * 4);
  int*   offs   = (int*)alloc(NEXP * 4);
  int*   pos    = (int*)alloc(NEXP * 4);

  (void)hipMemsetAsync(cnt, 0, NEXP * sizeof(int), stream);

  const int SB = (int)(TD / 4 / 256);
  split2_kernel<<<SB, 256, 0, stream>>>(x, xs0, xs1, TD);
  split2_kernel<<<SB, 256, 0, stream>>>(enc, es0, es1, TD);
  // stacked weight planes: self QKV rows 0..3071; cross KV rows 0..2047
  for (int s = 0; s < 3; ++s)
    wsplit2_kernel<<<dim3(32, 32, 1), 256, 0, stream>>>(aw[s], wqkv0 + (size_t)s * DIMc * DIMc, wqkv1 + (size_t)s * DIMc * DIMc, DIMc, DIMc);
  wsplit2_kernel<<<dim3(32, 32, 1), 256, 0, stream>>>(aw[5], wkv0, wkv1, DIMc, DIMc);
  wsplit2_kernel<<<dim3(32, 32, 1), 256, 0, stream>>>(aw[6], wkv0 + (size_t)DIMc * DIMc, wkv1 + (size_t)DIMc * DIMc, DIMc, DIMc);
  wsplit2_kernel<<<dim3(32, 32, 1), 256, 0, stream>>>(aw[4], wq0, wq1, DIMc, DIMc);
  wsplit2_kernel<<<dim3(32, 32, 1), 256, 0, stream>>>(aw[3], wo10, wo11, DIMc, DIMc);
  wsplit2_kernel<<<dim3(32, 32, 1), 256, 0, stream>>>(aw[7], wo20, wo21, DIMc, DIMc);
  wsplit1_kernel<<<dim3(FFD / 32, DIMc / 32, NEXP), 256, 0, stream>>>(e_w1, w1t, DIMc, FFD);
  wsplit1_kernel<<<dim3(DIMc / 32, FFD / 32, NEXP), 256, 0, stream>>>(e_w2, w2t, FFD, DIMc);
  biascat_kernel<<<20, 256, 0, stream>>>(ab[0], ab[1], ab[2], ab[5], ab[6], qkvb, kvb);

  const dim3 gproj(DIMc / 128, NTOK / 64, 1);        // MT=64
  const dim3 gqkv(3 * DIMc / 128, NTOK / 64, 1);     // MT=64
  const dim3 gkv(2 * DIMc / 128, NTOK / 64, 1);      // MT=64
  const dim3 gattn(SLENc / 128, NHEAD, NBAT);        // QBLK=128, 512 blocks
  const dim3 gvt(SLENc / 32, HDM / 32, NBAT * NHEAD);

  // ---- self-attention ----
  gemm_kernel<64, 32, true, false, 3><<<gqkv, 256, 0, stream>>>(xs0, xs1, wqkv0, wqkv1, qkvb, QKVh, QKVr, NTOK, 3 * DIMc, DIMc, nullptr, nullptr, nullptr);
  vtrans2_kernel<<<gvt, 256, 0, stream>>>(QKVh + 2048, QKVr + 2048, 3 * DIMc, Vth, Vtr);
  attn2_kernel<true><<<gattn, 512, 0, stream>>>(QKVh, QKVr, 3 * DIMc, QKVh + 1024, QKVr + 1024, 3 * DIMc, Vth, Vtr, os0, os1);
  gemm_kernel<64, 32, true, false, 0><<<gproj, 256, 0, stream>>>(os0, os1, wo10, wo11, ab[3], aout, nullptr, NTOK, DIMc, DIMc, nullptr, nullptr, nullptr);
  resln_kernel<2><<<NTOK, 256, 0, stream>>>(x, aout, ln1_g, ln1_b, x1, xs0, xs1);
  // ---- cross-attention ----
  gemm_kernel<64, 32, true, false, 3><<<gproj, 256, 0, stream>>>(xs0, xs1, wq0, wq1, ab[4], Qch, Qcr, NTOK, DIMc, DIMc, nullptr, nullptr, nullptr);
  gemm_kernel<64, 32, true, false, 3><<<gkv, 256, 0, stream>>>(es0, es1, wkv0, wkv1, kvb, KVh, KVr, NTOK, 2 * DIMc, DIMc, nullptr, nullptr, nullptr);
  vtrans2_kernel<<<gvt, 256, 0, stream>>>(KVh + 1024, KVr + 1024, 2 * DIMc, Vth, Vtr);
  attn2_kernel<false><<<gattn, 512, 0, stream>>>(Qch, Qcr, DIMc, KVh, KVr, 2 * DIMc, Vth, Vtr, os0, os1);
  gemm_kernel<64, 32, true, false, 0><<<gproj, 256, 0, stream>>>(os0, os1, wo20, wo21, ab[7], aout, nullptr, NTOK, DIMc, DIMc, nullptr, nullptr, nullptr);
  // ---- LN2 + fused router ----
  resln_router_kernel<<<NTOK, 256, 0, stream>>>(x1, aout, ln2_g, ln2_b, rw, rb, x2, x2h, topi, topwp, cnt);
  // ---- MoE (MT=128 for B-panel reuse; BK=32 pipelined double-buffer, 32KB LDS) ----
  scan_kernel<<<1, 64, 0, stream>>>(cnt, offs, pos);
  fill_kernel<<<NTOK / 256, 256, 0, stream>>>(topi, offs, pos, tlist, slotof);
  gemm_kernel<128, 32, false, true, 1><<<dim3(FFD / 128, NTOK / 128, NEXP), 256, 0, stream>>>(
      x2h, nullptr, w1t, nullptr, e_b1, hbuf, nullptr, NTOK, FFD, DIMc, tlist, cnt, offs);
  gemm_kernel<128, 32, false, false, 2><<<dim3(DIMc / 128, NTOK / 128, NEXP), 256, 0, stream>>>(
      hbuf, nullptr, w2t, nullptr, e_b2, eo, nullptr, NTOK, DIMc, FFD, nullptr, cnt, offs);
  final_kernel<<<NTOK, 256, 0, stream>>>(x2, eo, slotof, topwp, ln3_g, ln3_b, (float*)d_out);
}